// Round 1
// baseline (1435.910 us; speedup 1.0000x reference)
//
#include <hip/hip_runtime.h>
#include <cmath>

// CrossKDDenseNet fused block for MI355X (gfx950).
// B=32768 rows, D=688 = 4 heads x 172, MLP hidden 128.
// Strategy: bf16 MFMA GEMMs (16x16x32), fp32 accumulate, fp32 residual path.

#define B_ROWS 32768
#define D_DIM  688
#define DH_DIM 172
#define MH_DIM 128

typedef unsigned short ushort_t;
typedef __attribute__((ext_vector_type(8))) __bf16 bf16x8;
typedef __attribute__((ext_vector_type(4))) float  f32x4;

__device__ __forceinline__ float b2f(ushort_t u) {
    return __builtin_bit_cast(float, (unsigned int)u << 16);
}
__device__ __forceinline__ ushort_t f2bf(float f) {
    unsigned int u = __builtin_bit_cast(unsigned int, f);
    u += 0x7FFFu + ((u >> 16) & 1u);   // round-to-nearest-even (finite inputs)
    return (ushort_t)(u >> 16);
}

// ---------------- fp32 -> bf16 bulk convert (weights) ----------------
__global__ __launch_bounds__(256)
void cvt_f32_bf16(const float* __restrict__ src, ushort_t* __restrict__ dst, int n4) {
    int i = blockIdx.x * 256 + threadIdx.x;
    const int stride = gridDim.x * 256;
    for (; i < n4; i += stride) {
        float4 v = reinterpret_cast<const float4*>(src)[i];
        ushort4 o;
        o.x = f2bf(v.x); o.y = f2bf(v.y); o.z = f2bf(v.z); o.w = f2bf(v.w);
        reinterpret_cast<ushort4*>(dst)[i] = o;
    }
}

// ---------------- LayerNorm (wave per row, both streams) ----------------
__global__ __launch_bounds__(256)
void ln_kernel(const float* __restrict__ Xv, const float* __restrict__ Xi,
               const float* __restrict__ gv, const float* __restrict__ bv,
               const float* __restrict__ gi, const float* __restrict__ bi,
               ushort_t* __restrict__ Yv, ushort_t* __restrict__ Yi)
{
    const int lane = threadIdx.x & 63;
    const int wave = threadIdx.x >> 6;
    const long w = (long)blockIdx.x * 4 + wave;   // 0 .. 2B-1
    const float* X; const float* g; const float* b; ushort_t* Y; long r;
    if (w < B_ROWS) { X = Xv; g = gv; b = bv; Y = Yv; r = w; }
    else            { X = Xi; g = gi; b = bi; Y = Yi; r = w - B_ROWS; }

    const float4* row = reinterpret_cast<const float4*>(X + r * D_DIM);
    float4 v0 = row[lane];
    float4 v1 = row[lane + 64];
    float4 v2 = make_float4(0.f, 0.f, 0.f, 0.f);
    if (lane < 44) v2 = row[lane + 128];   // 172 float4 per row

    float s  = v0.x + v0.y + v0.z + v0.w + v1.x + v1.y + v1.z + v1.w
             + v2.x + v2.y + v2.z + v2.w;
    float s2 = v0.x*v0.x + v0.y*v0.y + v0.z*v0.z + v0.w*v0.w
             + v1.x*v1.x + v1.y*v1.y + v1.z*v1.z + v1.w*v1.w
             + v2.x*v2.x + v2.y*v2.y + v2.z*v2.z + v2.w*v2.w;
#pragma unroll
    for (int m = 32; m; m >>= 1) { s += __shfl_xor(s, m); s2 += __shfl_xor(s2, m); }

    const float mean = s * (1.f / 688.f);
    const float var  = s2 * (1.f / 688.f) - mean * mean;   // biased var
    const float rstd = rsqrtf(var + 1e-5f);

    const float4* g4 = reinterpret_cast<const float4*>(g);
    const float4* b4 = reinterpret_cast<const float4*>(b);
    ushort4* out4 = reinterpret_cast<ushort4*>(Y + r * D_DIM);

    {
        float4 gg = g4[lane], bb = b4[lane];
        ushort4 o;
        o.x = f2bf((v0.x - mean) * rstd * gg.x + bb.x);
        o.y = f2bf((v0.y - mean) * rstd * gg.y + bb.y);
        o.z = f2bf((v0.z - mean) * rstd * gg.z + bb.z);
        o.w = f2bf((v0.w - mean) * rstd * gg.w + bb.w);
        out4[lane] = o;
    }
    {
        float4 gg = g4[lane + 64], bb = b4[lane + 64];
        ushort4 o;
        o.x = f2bf((v1.x - mean) * rstd * gg.x + bb.x);
        o.y = f2bf((v1.y - mean) * rstd * gg.y + bb.y);
        o.z = f2bf((v1.z - mean) * rstd * gg.z + bb.z);
        o.w = f2bf((v1.w - mean) * rstd * gg.w + bb.w);
        out4[lane + 64] = o;
    }
    if (lane < 44) {
        float4 gg = g4[lane + 128], bb = b4[lane + 128];
        ushort4 o;
        o.x = f2bf((v2.x - mean) * rstd * gg.x + bb.x);
        o.y = f2bf((v2.y - mean) * rstd * gg.y + bb.y);
        o.z = f2bf((v2.z - mean) * rstd * gg.z + bb.z);
        o.w = f2bf((v2.w - mean) * rstd * gg.w + bb.w);
        out4[lane + 128] = o;
    }
}

// ---------------- GEMM: C(M,N) = A(M,K) @ W(N,K)^T  + epilogue ----------------
// MODE 0: out bf16 = v + bias
// MODE 1: out fp32 = cA*resid + cB*(v + bias)
// MODE 2: out bf16 = gelu_exact(v + bias)
template<int MODE>
__global__ __launch_bounds__(256)
void gemm_kernel(const ushort_t* __restrict__ A, const ushort_t* __restrict__ W,
                 const float* __restrict__ bias, void* __restrict__ outp,
                 const float* __restrict__ resid, const float* __restrict__ coef,
                 int ca, int cb, int M, int N, int K)
{
    __shared__ __align__(16) ushort_t As[128 * 32];
    __shared__ __align__(16) ushort_t Bs[128 * 32];
    const int tid  = threadIdx.x;
    const int lane = tid & 63;
    const int wave = tid >> 6;
    const int m0 = blockIdx.x * 128;
    const int n0 = blockIdx.y * 128;
    const int wm = (wave >> 1) * 64;
    const int wn = (wave & 1) * 64;

    const f32x4 vzero = {0.f, 0.f, 0.f, 0.f};
    f32x4 acc[4][4];
#pragma unroll
    for (int i = 0; i < 4; ++i)
#pragma unroll
        for (int j = 0; j < 4; ++j)
            acc[i][j] = vzero;

    const int nkt = (K + 31) / 32;
    for (int kt = 0; kt < nkt; ++kt) {
        const int kb = kt * 32;
#pragma unroll
        for (int s = 0; s < 2; ++s) {
            const int seg = tid + s * 256;
            const int row = seg >> 2;          // 0..127
            const int kk  = (seg & 3) * 8;     // 0,8,16,24
            const int gk  = kb + kk;
            uint4 av = make_uint4(0, 0, 0, 0);
            uint4 bv = make_uint4(0, 0, 0, 0);
            if (gk + 8 <= K) {                 // K is a multiple of 8 in all uses
                av = *reinterpret_cast<const uint4*>(A + (size_t)(m0 + row) * K + gk);
                const int nr = n0 + row;
                if (nr < N)
                    bv = *reinterpret_cast<const uint4*>(W + (size_t)nr * K + gk);
            }
            *reinterpret_cast<uint4*>(&As[row * 32 + kk]) = av;
            *reinterpret_cast<uint4*>(&Bs[row * 32 + kk]) = bv;
        }
        __syncthreads();

        bf16x8 af[4], bw[4];
        const int ko = (lane >> 4) * 8;
        const int rl = lane & 15;
#pragma unroll
        for (int i = 0; i < 4; ++i) {
            af[i] = *reinterpret_cast<const bf16x8*>(&As[(wm + i * 16 + rl) * 32 + ko]);
            bw[i] = *reinterpret_cast<const bf16x8*>(&Bs[(wn + i * 16 + rl) * 32 + ko]);
        }
#pragma unroll
        for (int i = 0; i < 4; ++i)
#pragma unroll
            for (int j = 0; j < 4; ++j)
                acc[i][j] = __builtin_amdgcn_mfma_f32_16x16x32_bf16(af[i], bw[j], acc[i][j], 0, 0, 0);
        __syncthreads();
    }

    float cA = 0.f, cB = 0.f;
    if constexpr (MODE == 1) { cA = coef[ca]; cB = coef[cb]; }
    const int rb = (lane >> 4) * 4;
    const int cl = lane & 15;
#pragma unroll
    for (int j = 0; j < 4; ++j) {
        const int col = n0 + wn + j * 16 + cl;
        if (col >= N) continue;
        const float bc = bias[col];
#pragma unroll
        for (int i = 0; i < 4; ++i) {
#pragma unroll
            for (int r = 0; r < 4; ++r) {
                const int row = m0 + wm + i * 16 + rb + r;   // M%128==0: always valid
                const size_t idx = (size_t)row * N + col;
                float v = acc[i][j][r] + bc;
                if constexpr (MODE == 0) {
                    ((ushort_t*)outp)[idx] = f2bf(v);
                } else if constexpr (MODE == 2) {
                    v = 0.5f * v * (1.0f + erff(v * 0.70710678118654752f));
                    ((ushort_t*)outp)[idx] = f2bf(v);
                } else {
                    ((float*)outp)[idx] = cA * resid[idx] + cB * v;
                }
            }
        }
    }
}

// ---------------- cross-attention over heads (wave per row) ----------------
__global__ __launch_bounds__(256)
void attn_kernel(const ushort_t* __restrict__ qkv_v, const ushort_t* __restrict__ qkv_i,
                 ushort_t* __restrict__ ctx_v, ushort_t* __restrict__ ctx_i)
{
    const int lane = threadIdx.x & 63;
    const int wave = threadIdx.x >> 6;
    const long r = (long)blockIdx.x * 4 + wave;
    const ushort_t* bv = qkv_v + r * (3 * D_DIM);   // [q(688)|k(688)|v(688)]
    const ushort_t* bi = qkv_i + r * (3 * D_DIM);

    float sv[4][4], si[4][4];
#pragma unroll
    for (int h = 0; h < 4; ++h)
#pragma unroll
        for (int g = 0; g < 4; ++g) { sv[h][g] = 0.f; si[h][g] = 0.f; }

    float vvr[3][4], vir[3][4];
#pragma unroll
    for (int it = 0; it < 3; ++it) {
        const int d = lane + it * 64;
        const bool ok = d < DH_DIM;
        float qv[4], kv[4], qi[4], ki[4];
#pragma unroll
        for (int h = 0; h < 4; ++h) {
            const int o = h * DH_DIM + d;
            qv[h]      = ok ? b2f(bv[o]) : 0.f;
            kv[h]      = ok ? b2f(bv[D_DIM + o]) : 0.f;
            vvr[it][h] = ok ? b2f(bv[2 * D_DIM + o]) : 0.f;
            qi[h]      = ok ? b2f(bi[o]) : 0.f;
            ki[h]      = ok ? b2f(bi[D_DIM + o]) : 0.f;
            vir[it][h] = ok ? b2f(bi[2 * D_DIM + o]) : 0.f;
        }
#pragma unroll
        for (int h = 0; h < 4; ++h)
#pragma unroll
            for (int g = 0; g < 4; ++g) {
                sv[h][g] += qi[h] * kv[g];   // att_vis scores: q_ir . k_vis
                si[h][g] += qv[h] * ki[g];   // att_ir  scores: q_vis . k_ir
            }
    }

#pragma unroll
    for (int h = 0; h < 4; ++h)
#pragma unroll
        for (int g = 0; g < 4; ++g) {
            float a = sv[h][g], b = si[h][g];
#pragma unroll
            for (int m = 32; m; m >>= 1) { a += __shfl_xor(a, m); b += __shfl_xor(b, m); }
            sv[h][g] = a; si[h][g] = b;
        }

    const float scale = 0.07624928516630235f;   // 1/sqrt(172)
    float av[4][4], ai[4][4];
#pragma unroll
    for (int h = 0; h < 4; ++h) {
        float m1 = fmaxf(fmaxf(sv[h][0], sv[h][1]), fmaxf(sv[h][2], sv[h][3])) * scale;
        float m2 = fmaxf(fmaxf(si[h][0], si[h][1]), fmaxf(si[h][2], si[h][3])) * scale;
        float d1 = 0.f, d2 = 0.f;
#pragma unroll
        for (int g = 0; g < 4; ++g) {
            av[h][g] = expf(sv[h][g] * scale - m1); d1 += av[h][g];
            ai[h][g] = expf(si[h][g] * scale - m2); d2 += ai[h][g];
        }
        const float r1 = 1.f / d1, r2 = 1.f / d2;
#pragma unroll
        for (int g = 0; g < 4; ++g) { av[h][g] *= r1; ai[h][g] *= r2; }
    }

#pragma unroll
    for (int it = 0; it < 3; ++it) {
        const int d = lane + it * 64;
        if (d < DH_DIM) {
#pragma unroll
            for (int h = 0; h < 4; ++h) {
                float cv = av[h][0] * vvr[it][0] + av[h][1] * vvr[it][1]
                         + av[h][2] * vvr[it][2] + av[h][3] * vvr[it][3];
                float ci = ai[h][0] * vir[it][0] + ai[h][1] * vir[it][1]
                         + ai[h][2] * vir[it][2] + ai[h][3] * vir[it][3];
                ctx_v[r * D_DIM + h * DH_DIM + d] = f2bf(cv);
                ctx_i[r * D_DIM + h * DH_DIM + d] = f2bf(ci);
            }
        }
    }
}

// ---------------- host launcher ----------------
extern "C" void kernel_launch(void* const* d_in, const int* in_sizes, int n_in,
                              void* d_out, int out_size, void* d_ws, size_t ws_size,
                              hipStream_t stream)
{
    if (n_in < 35) return;
    const float* x     = (const float*)d_in[0];
    const float* x2    = (const float*)d_in[1];
    const float* Wq_v  = (const float*)d_in[2];
    const float* bq_v  = (const float*)d_in[3];
    const float* Wk_v  = (const float*)d_in[4];
    const float* bk_v  = (const float*)d_in[5];
    const float* Wv_v  = (const float*)d_in[6];
    const float* bv_v  = (const float*)d_in[7];
    const float* Wq_i  = (const float*)d_in[8];
    const float* bq_i  = (const float*)d_in[9];
    const float* Wk_i  = (const float*)d_in[10];
    const float* bk_i  = (const float*)d_in[11];
    const float* Wv_i  = (const float*)d_in[12];
    const float* bv_i  = (const float*)d_in[13];
    const float* Wo_v  = (const float*)d_in[14];
    const float* bo_v  = (const float*)d_in[15];
    const float* Wo_i  = (const float*)d_in[16];
    const float* bo_i  = (const float*)d_in[17];
    const float* ln1_g = (const float*)d_in[18];
    const float* ln1_b = (const float*)d_in[19];
    const float* ln2_g = (const float*)d_in[20];
    const float* ln2_b = (const float*)d_in[21];
    const float* ln3_g = (const float*)d_in[22];
    const float* ln3_b = (const float*)d_in[23];
    const float* ln4_g = (const float*)d_in[24];
    const float* ln4_b = (const float*)d_in[25];
    const float* m1v_W = (const float*)d_in[26];
    const float* m1v_b = (const float*)d_in[27];
    const float* m2v_W = (const float*)d_in[28];
    const float* m2v_b = (const float*)d_in[29];
    const float* m1i_W = (const float*)d_in[30];
    const float* m1i_b = (const float*)d_in[31];
    const float* m2i_W = (const float*)d_in[32];
    const float* m2i_b = (const float*)d_in[33];
    const float* coef  = (const float*)d_in[34];

    const size_t BD = (size_t)B_ROWS * D_DIM;

    char* ws = (char*)d_ws;
    size_t off = 0;
    auto give = [&](size_t bytes) {
        char* p = ws + off;
        off += (bytes + 255) & ~(size_t)255;
        return p;
    };
    ushort_t* Wcat_v = (ushort_t*)give(2064ull * 688 * 2);
    ushort_t* Wcat_i = (ushort_t*)give(2064ull * 688 * 2);
    ushort_t* Wo_vb  = (ushort_t*)give(688ull * 688 * 2);
    ushort_t* Wo_ib  = (ushort_t*)give(688ull * 688 * 2);
    ushort_t* m1vb   = (ushort_t*)give(128ull * 688 * 2);
    ushort_t* m1ib   = (ushort_t*)give(128ull * 688 * 2);
    ushort_t* m2vb   = (ushort_t*)give(688ull * 128 * 2);
    ushort_t* m2ib   = (ushort_t*)give(688ull * 128 * 2);
    float*    bcat_v = (float*)give(2064 * 4);
    float*    bcat_i = (float*)give(2064 * 4);
    // region A: xn (2*BD bf16) + qkv (2*3BD bf16)
    char* regA = give(BD * 2 * 2 + BD * 3 * 2 * 2);
    // region C: ctx (2*BD bf16); reused later as LN3/4 output h
    char* regC = give(BD * 2 * 2);
    // region G: mlp hidden (2 * B*128 bf16)
    char* regG = give((size_t)B_ROWS * MH_DIM * 2 * 2);
    if (ws_size < off) return;   // not enough scratch; bail (will fail validation loudly)

    ushort_t* xn_v  = (ushort_t*)regA;
    ushort_t* xn_i  = xn_v + BD;
    ushort_t* qkv_v = xn_i + BD;
    ushort_t* qkv_i = qkv_v + BD * 3;
    ushort_t* ctx_v = (ushort_t*)regC;
    ushort_t* ctx_i = ctx_v + BD;
    ushort_t* h_v   = ctx_v;              // reuse after out-proj consumes ctx
    ushort_t* h_i   = ctx_i;
    ushort_t* g_v   = (ushort_t*)regG;
    ushort_t* g_i   = g_v + (size_t)B_ROWS * MH_DIM;

    float* ov = (float*)d_out;            // out_vis intermediate lives in d_out (fp32)
    float* oi = ov + BD;

    auto cvt = [&](const float* s, ushort_t* d, int n) {
        int n4 = n / 4;
        int blocks = (n4 + 255) / 256;
        if (blocks > 1024) blocks = 1024;
        cvt_f32_bf16<<<dim3(blocks), dim3(256), 0, stream>>>(s, d, n4);
    };
    const int DD = D_DIM * D_DIM;
    cvt(Wq_v, Wcat_v,          DD);
    cvt(Wk_v, Wcat_v + DD,     DD);
    cvt(Wv_v, Wcat_v + 2 * DD, DD);
    cvt(Wq_i, Wcat_i,          DD);
    cvt(Wk_i, Wcat_i + DD,     DD);
    cvt(Wv_i, Wcat_i + 2 * DD, DD);
    cvt(Wo_v, Wo_vb, DD);
    cvt(Wo_i, Wo_ib, DD);
    cvt(m1v_W, m1vb, MH_DIM * D_DIM);
    cvt(m1i_W, m1ib, MH_DIM * D_DIM);
    cvt(m2v_W, m2vb, D_DIM * MH_DIM);
    cvt(m2i_W, m2ib, D_DIM * MH_DIM);

    hipMemcpyAsync(bcat_v,        bq_v, D_DIM * 4, hipMemcpyDeviceToDevice, stream);
    hipMemcpyAsync(bcat_v + 688,  bk_v, D_DIM * 4, hipMemcpyDeviceToDevice, stream);
    hipMemcpyAsync(bcat_v + 1376, bv_v, D_DIM * 4, hipMemcpyDeviceToDevice, stream);
    hipMemcpyAsync(bcat_i,        bq_i, D_DIM * 4, hipMemcpyDeviceToDevice, stream);
    hipMemcpyAsync(bcat_i + 688,  bk_i, D_DIM * 4, hipMemcpyDeviceToDevice, stream);
    hipMemcpyAsync(bcat_i + 1376, bv_i, D_DIM * 4, hipMemcpyDeviceToDevice, stream);

    // LN1 / LN2
    ln_kernel<<<dim3(2 * B_ROWS / 4), dim3(256), 0, stream>>>(
        x, x2, ln1_g, ln1_b, ln2_g, ln2_b, xn_v, xn_i);

    // QKV projections (fused q|k|v): (B,688) @ (2064,688)^T
    dim3 gq(B_ROWS / 128, (2064 + 127) / 128);
    gemm_kernel<0><<<gq, dim3(256), 0, stream>>>(xn_v, Wcat_v, bcat_v, qkv_v,
                                                 nullptr, nullptr, 0, 0, B_ROWS, 2064, 688);
    gemm_kernel<0><<<gq, dim3(256), 0, stream>>>(xn_i, Wcat_i, bcat_i, qkv_i,
                                                 nullptr, nullptr, 0, 0, B_ROWS, 2064, 688);

    // per-row 4x4 cross attention
    attn_kernel<<<dim3(B_ROWS / 4), dim3(256), 0, stream>>>(qkv_v, qkv_i, ctx_v, ctx_i);

    // out projections + residual -> fp32 d_out
    dim3 go(B_ROWS / 128, (D_DIM + 127) / 128);
    gemm_kernel<1><<<go, dim3(256), 0, stream>>>(ctx_v, Wo_vb, bo_v, ov,
                                                 x,  coef, 0, 1, B_ROWS, D_DIM, 688);
    gemm_kernel<1><<<go, dim3(256), 0, stream>>>(ctx_i, Wo_ib, bo_i, oi,
                                                 x2, coef, 2, 3, B_ROWS, D_DIM, 688);

    // LN3 / LN4
    ln_kernel<<<dim3(2 * B_ROWS / 4), dim3(256), 0, stream>>>(
        ov, oi, ln3_g, ln3_b, ln4_g, ln4_b, h_v, h_i);

    // MLP fc1 + exact gelu
    dim3 gm1(B_ROWS / 128, 1);
    gemm_kernel<2><<<gm1, dim3(256), 0, stream>>>(h_v, m1vb, m1v_b, g_v,
                                                  nullptr, nullptr, 0, 0, B_ROWS, MH_DIM, 688);
    gemm_kernel<2><<<gm1, dim3(256), 0, stream>>>(h_i, m1ib, m1i_b, g_i,
                                                  nullptr, nullptr, 0, 0, B_ROWS, MH_DIM, 688);

    // MLP fc2 + final residual (in-place RMW on d_out, per-element same-thread)
    dim3 gm2(B_ROWS / 128, (D_DIM + 127) / 128);
    gemm_kernel<1><<<gm2, dim3(256), 0, stream>>>(g_v, m2vb, m2v_b, ov,
                                                  ov, coef, 4, 5, B_ROWS, D_DIM, MH_DIM);
    gemm_kernel<1><<<gm2, dim3(256), 0, stream>>>(g_i, m2ib, m2i_b, oi,
                                                  oi, coef, 6, 7, B_ROWS, D_DIM, MH_DIM);
}

// Round 2
// 938.362 us; speedup vs baseline: 1.5302x; 1.5302x over previous
//
#include <hip/hip_runtime.h>
#include <cmath>

// CrossKDDenseNet fused block for MI355X (gfx950).
// B=32768 rows, D=688 = 4 heads x 172, MLP hidden 128.
// Round 2: global_load_lds(16B) staging, K padded to 704, guard-free GEMM
// main loop, grid.z=2 stream fusion, fewer dispatches.

#define B_ROWS 32768
#define D_DIM  688
#define DP     704     // padded K / activation stride
#define DH_DIM 172
#define MH_DIM 128

typedef unsigned short ushort_t;
typedef __attribute__((ext_vector_type(8))) __bf16 bf16x8;
typedef __attribute__((ext_vector_type(4))) float  f32x4;

__device__ __forceinline__ float b2f(ushort_t u) {
    return __builtin_bit_cast(float, (unsigned int)u << 16);
}
__device__ __forceinline__ ushort_t f2bf(float f) {
    unsigned int u = __builtin_bit_cast(unsigned int, f);
    u += 0x7FFFu + ((u >> 16) & 1u);   // round-to-nearest-even (finite inputs)
    return (ushort_t)(u >> 16);
}

__device__ __forceinline__ void gl2lds16(const ushort_t* g, ushort_t* l) {
    __builtin_amdgcn_global_load_lds(
        (const __attribute__((address_space(1))) unsigned int*)g,
        (__attribute__((address_space(3))) unsigned int*)l, 16, 0, 0);
}

// ---------------- fp32 -> bf16 convert with row/col zero padding ----------------
// src: (O, Kin) fp32 row-major.  dst: (Opad, Kpad) bf16 row-major, zero-filled pad.
__global__ __launch_bounds__(256)
void cvt_pad(const float* __restrict__ src, ushort_t* __restrict__ dst,
             int O, int Opad, int Kin, int Kpad)
{
    const int cpr = Kpad >> 3;              // 16B chunks per dst row
    const int total = Opad * cpr;
    int t = blockIdx.x * 256 + threadIdx.x;
    if (t >= total) return;
    const int o = t / cpr;
    const int c = t - o * cpr;
    unsigned int p0 = 0, p1 = 0, p2 = 0, p3 = 0;
    if (o < O && (c * 8 + 8) <= Kin) {
        const float* s = src + (size_t)o * Kin + c * 8;
        float4 f0 = reinterpret_cast<const float4*>(s)[0];
        float4 f1 = reinterpret_cast<const float4*>(s)[1];
        p0 = f2bf(f0.x) | ((unsigned int)f2bf(f0.y) << 16);
        p1 = f2bf(f0.z) | ((unsigned int)f2bf(f0.w) << 16);
        p2 = f2bf(f1.x) | ((unsigned int)f2bf(f1.y) << 16);
        p3 = f2bf(f1.z) | ((unsigned int)f2bf(f1.w) << 16);
    }
    uint4 u = make_uint4(p0, p1, p2, p3);
    *reinterpret_cast<uint4*>(dst + (size_t)o * Kpad + c * 8) = u;
}

// ---------------- concat 3 biases per stream (replaces 6 memcpys) ----------------
__global__ __launch_bounds__(256)
void pack_bias(const float* __restrict__ a0, const float* __restrict__ a1,
               const float* __restrict__ a2, const float* __restrict__ b0,
               const float* __restrict__ b1, const float* __restrict__ b2,
               float* __restrict__ dv, float* __restrict__ di)
{
    int t = blockIdx.x * 256 + threadIdx.x;
    if (t >= 2064) return;
    float v, w;
    if (t < 688)       { v = a0[t];        w = b0[t]; }
    else if (t < 1376) { v = a1[t - 688];  w = b1[t - 688]; }
    else               { v = a2[t - 1376]; w = b2[t - 1376]; }
    dv[t] = v; di[t] = w;
}

// ---------------- LayerNorm (wave per row, both streams); out stride DP ----------------
__global__ __launch_bounds__(256)
void ln_kernel(const float* __restrict__ Xv, const float* __restrict__ Xi,
               const float* __restrict__ gv, const float* __restrict__ bv,
               const float* __restrict__ gi, const float* __restrict__ bi,
               ushort_t* __restrict__ Yv, ushort_t* __restrict__ Yi)
{
    const int lane = threadIdx.x & 63;
    const int wave = threadIdx.x >> 6;
    const long w = (long)blockIdx.x * 4 + wave;   // 0 .. 2B-1
    const float* X; const float* g; const float* b; ushort_t* Y; long r;
    if (w < B_ROWS) { X = Xv; g = gv; b = bv; Y = Yv; r = w; }
    else            { X = Xi; g = gi; b = bi; Y = Yi; r = w - B_ROWS; }

    const float4* row = reinterpret_cast<const float4*>(X + r * D_DIM);
    float4 v0 = row[lane];
    float4 v1 = row[lane + 64];
    float4 v2 = make_float4(0.f, 0.f, 0.f, 0.f);
    if (lane < 44) v2 = row[lane + 128];   // 172 float4 per row

    float s  = v0.x + v0.y + v0.z + v0.w + v1.x + v1.y + v1.z + v1.w
             + v2.x + v2.y + v2.z + v2.w;
    float s2 = v0.x*v0.x + v0.y*v0.y + v0.z*v0.z + v0.w*v0.w
             + v1.x*v1.x + v1.y*v1.y + v1.z*v1.z + v1.w*v1.w
             + v2.x*v2.x + v2.y*v2.y + v2.z*v2.z + v2.w*v2.w;
#pragma unroll
    for (int m = 32; m; m >>= 1) { s += __shfl_xor(s, m); s2 += __shfl_xor(s2, m); }

    const float mean = s * (1.f / 688.f);
    const float var  = s2 * (1.f / 688.f) - mean * mean;   // biased var
    const float rstd = rsqrtf(var + 1e-5f);

    const float4* g4 = reinterpret_cast<const float4*>(g);
    const float4* b4 = reinterpret_cast<const float4*>(b);
    ushort4* out4 = reinterpret_cast<ushort4*>(Y + r * DP);

    {
        float4 gg = g4[lane], bb = b4[lane];
        ushort4 o;
        o.x = f2bf((v0.x - mean) * rstd * gg.x + bb.x);
        o.y = f2bf((v0.y - mean) * rstd * gg.y + bb.y);
        o.z = f2bf((v0.z - mean) * rstd * gg.z + bb.z);
        o.w = f2bf((v0.w - mean) * rstd * gg.w + bb.w);
        out4[lane] = o;
    }
    {
        float4 gg = g4[lane + 64], bb = b4[lane + 64];
        ushort4 o;
        o.x = f2bf((v1.x - mean) * rstd * gg.x + bb.x);
        o.y = f2bf((v1.y - mean) * rstd * gg.y + bb.y);
        o.z = f2bf((v1.z - mean) * rstd * gg.z + bb.z);
        o.w = f2bf((v1.w - mean) * rstd * gg.w + bb.w);
        out4[lane + 64] = o;
    }
    if (lane < 44) {
        float4 gg = g4[lane + 128], bb = b4[lane + 128];
        ushort4 o;
        o.x = f2bf((v2.x - mean) * rstd * gg.x + bb.x);
        o.y = f2bf((v2.y - mean) * rstd * gg.y + bb.y);
        o.z = f2bf((v2.z - mean) * rstd * gg.z + bb.z);
        o.w = f2bf((v2.w - mean) * rstd * gg.w + bb.w);
        out4[lane + 128] = o;
    } else if (lane < 48) {
        out4[lane + 128] = make_ushort4(0, 0, 0, 0);   // zero K-pad 688..703
    }
}

// ---------------- GEMM: C(M,N) = A(M,K) @ W(N,K)^T + epilogue ----------------
// Guard-free staging: K%32==0, A has M rows stride lda, W has >= gridY*128 rows
// stride ldw (pad rows zeroed). grid.z selects the (vis, ir) stream.
// MODE 0: out bf16 = v + bias
// MODE 1: out fp32 = cA*resid + cB*(v + bias)
// MODE 2: out bf16 = gelu_exact(v + bias)
template<int MODE>
__global__ __launch_bounds__(256, 4)
void gemm2(const ushort_t* __restrict__ A0, const ushort_t* __restrict__ A1,
           const ushort_t* __restrict__ W0, const ushort_t* __restrict__ W1,
           const float* __restrict__ bias0, const float* __restrict__ bias1,
           void* __restrict__ out0, void* __restrict__ out1,
           const float* __restrict__ res0, const float* __restrict__ res1,
           const float* __restrict__ coef,
           int ca0, int cb0, int ca1, int cb1,
           int N, int K, int lda, int ldw, int ldo)
{
    __shared__ __align__(16) ushort_t As[128 * 32];
    __shared__ __align__(16) ushort_t Bs[128 * 32];
    const int zz = blockIdx.z;
    const ushort_t* A = zz ? A1 : A0;
    const ushort_t* W = zz ? W1 : W0;
    const float* bias = zz ? bias1 : bias0;
    void* outp        = zz ? out1 : out0;
    const float* resid = zz ? res1 : res0;
    const int ca = zz ? ca1 : ca0;
    const int cb = zz ? cb1 : cb0;

    const int tid  = threadIdx.x;
    const int lane = tid & 63;
    const int wave = tid >> 6;
    const int m0 = blockIdx.x * 128;
    const int n0 = blockIdx.y * 128;
    const int wm = (wave >> 1) * 64;
    const int wn = (wave & 1) * 64;

    // staging: 512 x 16B segments per matrix per K-step; wave w owns segs
    // [w*128, w*128+128) via two global_load_lds issues of 64 lanes each.
    const int s0 = wave * 128 + lane;
    const int s1 = s0 + 64;
    const ushort_t* pa0 = A + (size_t)(m0 + (s0 >> 2)) * lda + (s0 & 3) * 8;
    const ushort_t* pa1 = A + (size_t)(m0 + (s1 >> 2)) * lda + (s1 & 3) * 8;
    const ushort_t* pb0 = W + (size_t)(n0 + (s0 >> 2)) * ldw + (s0 & 3) * 8;
    const ushort_t* pb1 = W + (size_t)(n0 + (s1 >> 2)) * ldw + (s1 & 3) * 8;
    ushort_t* la0 = &As[(wave * 128) * 8];        // wave-uniform LDS bases
    ushort_t* la1 = &As[(wave * 128 + 64) * 8];
    ushort_t* lb0 = &Bs[(wave * 128) * 8];
    ushort_t* lb1 = &Bs[(wave * 128 + 64) * 8];

    const f32x4 vzero = {0.f, 0.f, 0.f, 0.f};
    f32x4 acc[4][4];
#pragma unroll
    for (int i = 0; i < 4; ++i)
#pragma unroll
        for (int j = 0; j < 4; ++j)
            acc[i][j] = vzero;

    const int ko = (lane >> 4) * 8;
    const int rl = lane & 15;

    for (int kb = 0; kb < K; kb += 32) {
        gl2lds16(pa0, la0); gl2lds16(pa1, la1);
        gl2lds16(pb0, lb0); gl2lds16(pb1, lb1);
        pa0 += 32; pa1 += 32; pb0 += 32; pb1 += 32;
        __syncthreads();                 // drains vmcnt before barrier

        bf16x8 af[4], bw[4];
#pragma unroll
        for (int i = 0; i < 4; ++i) {
            af[i] = *reinterpret_cast<const bf16x8*>(&As[(wm + i * 16 + rl) * 32 + ko]);
            bw[i] = *reinterpret_cast<const bf16x8*>(&Bs[(wn + i * 16 + rl) * 32 + ko]);
        }
#pragma unroll
        for (int i = 0; i < 4; ++i)
#pragma unroll
            for (int j = 0; j < 4; ++j)
                acc[i][j] = __builtin_amdgcn_mfma_f32_16x16x32_bf16(af[i], bw[j], acc[i][j], 0, 0, 0);
        __syncthreads();
    }

    float cA = 0.f, cB = 0.f;
    if constexpr (MODE == 1) { cA = coef[ca]; cB = coef[cb]; }
    const int rb = (lane >> 4) * 4;
    const int cl = lane & 15;
#pragma unroll
    for (int j = 0; j < 4; ++j) {
        const int col = n0 + wn + j * 16 + cl;
        if (col >= N) continue;
        const float bc = bias[col];
#pragma unroll
        for (int i = 0; i < 4; ++i) {
#pragma unroll
            for (int r = 0; r < 4; ++r) {
                const int row = m0 + wm + i * 16 + rb + r;   // M%128==0: always valid
                const size_t idx = (size_t)row * ldo + col;
                float v = acc[i][j][r] + bc;
                if constexpr (MODE == 0) {
                    ((ushort_t*)outp)[idx] = f2bf(v);
                } else if constexpr (MODE == 2) {
                    v = 0.5f * v * (1.0f + erff(v * 0.70710678118654752f));
                    ((ushort_t*)outp)[idx] = f2bf(v);
                } else {
                    ((float*)outp)[idx] = cA * resid[idx] + cB * v;
                }
            }
        }
    }
}

// ---------------- cross-attention over heads (wave per row) ----------------
// qkv rows stride 2064 (q|k|v of 688 each); ctx rows stride DP, K-pad zeroed.
__global__ __launch_bounds__(256)
void attn_kernel(const ushort_t* __restrict__ qkv_v, const ushort_t* __restrict__ qkv_i,
                 ushort_t* __restrict__ ctx_v, ushort_t* __restrict__ ctx_i)
{
    const int lane = threadIdx.x & 63;
    const int wave = threadIdx.x >> 6;
    const long r = (long)blockIdx.x * 4 + wave;
    const ushort_t* bv = qkv_v + r * 2064;
    const ushort_t* bi = qkv_i + r * 2064;

    float sv[4][4], si[4][4];
#pragma unroll
    for (int h = 0; h < 4; ++h)
#pragma unroll
        for (int g = 0; g < 4; ++g) { sv[h][g] = 0.f; si[h][g] = 0.f; }

    float vvr[3][4], vir[3][4];
#pragma unroll
    for (int it = 0; it < 3; ++it) {
        const int d = lane + it * 64;
        const bool ok = d < DH_DIM;
        float qv[4], kv[4], qi[4], ki[4];
#pragma unroll
        for (int h = 0; h < 4; ++h) {
            const int o = h * DH_DIM + d;
            qv[h]      = ok ? b2f(bv[o]) : 0.f;
            kv[h]      = ok ? b2f(bv[D_DIM + o]) : 0.f;
            vvr[it][h] = ok ? b2f(bv[2 * D_DIM + o]) : 0.f;
            qi[h]      = ok ? b2f(bi[o]) : 0.f;
            ki[h]      = ok ? b2f(bi[D_DIM + o]) : 0.f;
            vir[it][h] = ok ? b2f(bi[2 * D_DIM + o]) : 0.f;
        }
#pragma unroll
        for (int h = 0; h < 4; ++h)
#pragma unroll
            for (int g = 0; g < 4; ++g) {
                sv[h][g] += qi[h] * kv[g];   // att_vis scores: q_ir . k_vis
                si[h][g] += qv[h] * ki[g];   // att_ir  scores: q_vis . k_ir
            }
    }

#pragma unroll
    for (int h = 0; h < 4; ++h)
#pragma unroll
        for (int g = 0; g < 4; ++g) {
            float a = sv[h][g], b = si[h][g];
#pragma unroll
            for (int m = 32; m; m >>= 1) { a += __shfl_xor(a, m); b += __shfl_xor(b, m); }
            sv[h][g] = a; si[h][g] = b;
        }

    const float scale = 0.07624928516630235f;   // 1/sqrt(172)
    float av[4][4], ai[4][4];
#pragma unroll
    for (int h = 0; h < 4; ++h) {
        float m1 = fmaxf(fmaxf(sv[h][0], sv[h][1]), fmaxf(sv[h][2], sv[h][3])) * scale;
        float m2 = fmaxf(fmaxf(si[h][0], si[h][1]), fmaxf(si[h][2], si[h][3])) * scale;
        float d1 = 0.f, d2 = 0.f;
#pragma unroll
        for (int g = 0; g < 4; ++g) {
            av[h][g] = expf(sv[h][g] * scale - m1); d1 += av[h][g];
            ai[h][g] = expf(si[h][g] * scale - m2); d2 += ai[h][g];
        }
        const float r1 = 1.f / d1, r2 = 1.f / d2;
#pragma unroll
        for (int g = 0; g < 4; ++g) { av[h][g] *= r1; ai[h][g] *= r2; }
    }

#pragma unroll
    for (int it = 0; it < 3; ++it) {
        const int d = lane + it * 64;
        if (d < DH_DIM) {
#pragma unroll
            for (int h = 0; h < 4; ++h) {
                float cv = av[h][0] * vvr[it][0] + av[h][1] * vvr[it][1]
                         + av[h][2] * vvr[it][2] + av[h][3] * vvr[it][3];
                float ci = ai[h][0] * vir[it][0] + ai[h][1] * vir[it][1]
                         + ai[h][2] * vir[it][2] + ai[h][3] * vir[it][3];
                ctx_v[r * DP + h * DH_DIM + d] = f2bf(cv);
                ctx_i[r * DP + h * DH_DIM + d] = f2bf(ci);
            }
        }
    }
    if (lane < 16) {                       // zero K-pad 688..703
        ctx_v[r * DP + 688 + lane] = 0;
        ctx_i[r * DP + 688 + lane] = 0;
    }
}

// ---------------- host launcher ----------------
extern "C" void kernel_launch(void* const* d_in, const int* in_sizes, int n_in,
                              void* d_out, int out_size, void* d_ws, size_t ws_size,
                              hipStream_t stream)
{
    if (n_in < 35) return;
    const float* x     = (const float*)d_in[0];
    const float* x2    = (const float*)d_in[1];
    const float* Wq_v  = (const float*)d_in[2];
    const float* bq_v  = (const float*)d_in[3];
    const float* Wk_v  = (const float*)d_in[4];
    const float* bk_v  = (const float*)d_in[5];
    const float* Wv_v  = (const float*)d_in[6];
    const float* bv_v  = (const float*)d_in[7];
    const float* Wq_i  = (const float*)d_in[8];
    const float* bq_i  = (const float*)d_in[9];
    const float* Wk_i  = (const float*)d_in[10];
    const float* bk_i  = (const float*)d_in[11];
    const float* Wv_i  = (const float*)d_in[12];
    const float* bv_i  = (const float*)d_in[13];
    const float* Wo_v  = (const float*)d_in[14];
    const float* bo_v  = (const float*)d_in[15];
    const float* Wo_i  = (const float*)d_in[16];
    const float* bo_i  = (const float*)d_in[17];
    const float* ln1_g = (const float*)d_in[18];
    const float* ln1_b = (const float*)d_in[19];
    const float* ln2_g = (const float*)d_in[20];
    const float* ln2_b = (const float*)d_in[21];
    const float* ln3_g = (const float*)d_in[22];
    const float* ln3_b = (const float*)d_in[23];
    const float* ln4_g = (const float*)d_in[24];
    const float* ln4_b = (const float*)d_in[25];
    const float* m1v_W = (const float*)d_in[26];
    const float* m1v_b = (const float*)d_in[27];
    const float* m2v_W = (const float*)d_in[28];
    const float* m2v_b = (const float*)d_in[29];
    const float* m1i_W = (const float*)d_in[30];
    const float* m1i_b = (const float*)d_in[31];
    const float* m2i_W = (const float*)d_in[32];
    const float* m2i_b = (const float*)d_in[33];
    const float* coef  = (const float*)d_in[34];

    const size_t BDP = (size_t)B_ROWS * DP;
    const size_t BD  = (size_t)B_ROWS * D_DIM;

    char* ws = (char*)d_ws;
    size_t off = 0;
    auto give = [&](size_t bytes) {
        char* p = ws + off;
        off += (bytes + 255) & ~(size_t)255;
        return p;
    };
    ushort_t* Wcat_v = (ushort_t*)give(2176ull * DP * 2);
    ushort_t* Wcat_i = (ushort_t*)give(2176ull * DP * 2);
    ushort_t* Wo_vb  = (ushort_t*)give(768ull * DP * 2);
    ushort_t* Wo_ib  = (ushort_t*)give(768ull * DP * 2);
    ushort_t* m1vb   = (ushort_t*)give(128ull * DP * 2);
    ushort_t* m1ib   = (ushort_t*)give(128ull * DP * 2);
    ushort_t* m2vb   = (ushort_t*)give(768ull * 128 * 2);
    ushort_t* m2ib   = (ushort_t*)give(768ull * 128 * 2);
    float*    bcat_v = (float*)give(2064 * 4);
    float*    bcat_i = (float*)give(2064 * 4);
    // region X: xn (2*BDP bf16) -> dead after QKV gemm; reused for ctx, then h
    char* regX = give(BDP * 2 * 2);
    // region Q: qkv (2 * B * 2064 bf16)
    char* regQ = give((size_t)B_ROWS * 2064 * 2 * 2);
    // region G: mlp hidden (2 * B*128 bf16)
    char* regG = give((size_t)B_ROWS * MH_DIM * 2 * 2);
    if (ws_size < off) return;   // not enough scratch; fail loudly via validation

    ushort_t* xn_v  = (ushort_t*)regX;
    ushort_t* xn_i  = xn_v + BDP;
    ushort_t* ctx_v = xn_v;               // alias: xn dead after QKV gemm
    ushort_t* ctx_i = xn_i;
    ushort_t* h_v   = ctx_v;              // alias: ctx dead after out-proj
    ushort_t* h_i   = ctx_i;
    ushort_t* qkv_v = (ushort_t*)regQ;
    ushort_t* qkv_i = qkv_v + (size_t)B_ROWS * 2064;
    ushort_t* g_v   = (ushort_t*)regG;
    ushort_t* g_i   = g_v + (size_t)B_ROWS * MH_DIM;

    float* ov = (float*)d_out;            // out_vis fp32 lives in d_out
    float* oi = ov + BD;

    auto cvt = [&](const float* s, ushort_t* d, int O, int Opad, int Kin, int Kpad) {
        int total = Opad * (Kpad >> 3);
        cvt_pad<<<dim3((total + 255) / 256), dim3(256), 0, stream>>>(s, d, O, Opad, Kin, Kpad);
    };
    cvt(Wq_v, Wcat_v,             688, 688, 688, DP);
    cvt(Wk_v, Wcat_v + 688 * DP,  688, 688, 688, DP);
    cvt(Wv_v, Wcat_v + 1376 * DP, 688, 800, 688, DP);   // rows 2064..2175 zeroed
    cvt(Wq_i, Wcat_i,             688, 688, 688, DP);
    cvt(Wk_i, Wcat_i + 688 * DP,  688, 688, 688, DP);
    cvt(Wv_i, Wcat_i + 1376 * DP, 688, 800, 688, DP);
    cvt(Wo_v, Wo_vb, 688, 768, 688, DP);
    cvt(Wo_i, Wo_ib, 688, 768, 688, DP);
    cvt(m1v_W, m1vb, 128, 128, 688, DP);
    cvt(m1i_W, m1ib, 128, 128, 688, DP);
    cvt(m2v_W, m2vb, 688, 768, 128, 128);
    cvt(m2i_W, m2ib, 688, 768, 128, 128);

    pack_bias<<<dim3(9), dim3(256), 0, stream>>>(bq_v, bk_v, bv_v, bq_i, bk_i, bv_i,
                                                 bcat_v, bcat_i);

    // LN1 / LN2 -> xn (stride DP, zero pad)
    ln_kernel<<<dim3(2 * B_ROWS / 4), dim3(256), 0, stream>>>(
        x, x2, ln1_g, ln1_b, ln2_g, ln2_b, xn_v, xn_i);

    // QKV projections, both streams: (B,704) @ (2176,704)^T -> (B,2064)
    gemm2<0><<<dim3(B_ROWS / 128, 17, 2), dim3(256), 0, stream>>>(
        xn_v, xn_i, Wcat_v, Wcat_i, bcat_v, bcat_i, qkv_v, qkv_i,
        nullptr, nullptr, nullptr, 0, 0, 0, 0, 2064, DP, DP, DP, 2064);

    // per-row 4x4 cross attention -> ctx (stride DP)
    attn_kernel<<<dim3(B_ROWS / 4), dim3(256), 0, stream>>>(qkv_v, qkv_i, ctx_v, ctx_i);

    // out projections + residual -> fp32 d_out
    gemm2<1><<<dim3(B_ROWS / 128, 6, 2), dim3(256), 0, stream>>>(
        ctx_v, ctx_i, Wo_vb, Wo_ib, bo_v, bo_i, ov, oi,
        x, x2, coef, 0, 1, 2, 3, 688, DP, DP, DP, 688);

    // LN3 / LN4 -> h (stride DP)
    ln_kernel<<<dim3(2 * B_ROWS / 4), dim3(256), 0, stream>>>(
        ov, oi, ln3_g, ln3_b, ln4_g, ln4_b, h_v, h_i);

    // MLP fc1 + exact gelu -> g (B,128)
    gemm2<2><<<dim3(B_ROWS / 128, 1, 2), dim3(256), 0, stream>>>(
        h_v, h_i, m1vb, m1ib, m1v_b, m1i_b, g_v, g_i,
        nullptr, nullptr, nullptr, 0, 0, 0, 0, 128, DP, DP, DP, 128);

    // MLP fc2 + final residual (in-place RMW on d_out, same-thread per element)
    gemm2<1><<<dim3(B_ROWS / 128, 6, 2), dim3(256), 0, stream>>>(
        g_v, g_i, m2vb, m2ib, m2v_b, m2i_b, ov, oi,
        ov, oi, coef, 4, 5, 6, 7, 688, 128, 128, 128, 688);
}

// Round 3
// 819.510 us; speedup vs baseline: 1.7522x; 1.1450x over previous
//
#include <hip/hip_runtime.h>
#include <cmath>

// CrossKDDenseNet fused block for MI355X (gfx950).
// B=32768 rows, D=688 = 4 heads x 172, MLP hidden 128.
// Round 3: XCD-swizzled 1D grid with N-fastest decode (A-strip L2 reuse),
// single merged weight-convert dispatch.

#define B_ROWS 32768
#define D_DIM  688
#define DP     704     // padded K / activation stride
#define DH_DIM 172
#define MH_DIM 128

typedef unsigned short ushort_t;
typedef __attribute__((ext_vector_type(8))) __bf16 bf16x8;
typedef __attribute__((ext_vector_type(4))) float  f32x4;

__device__ __forceinline__ float b2f(ushort_t u) {
    return __builtin_bit_cast(float, (unsigned int)u << 16);
}
__device__ __forceinline__ ushort_t f2bf(float f) {
    unsigned int u = __builtin_bit_cast(unsigned int, f);
    u += 0x7FFFu + ((u >> 16) & 1u);   // round-to-nearest-even (finite inputs)
    return (ushort_t)(u >> 16);
}

__device__ __forceinline__ void gl2lds16(const ushort_t* g, ushort_t* l) {
    __builtin_amdgcn_global_load_lds(
        (const __attribute__((address_space(1))) unsigned int*)g,
        (__attribute__((address_space(3))) unsigned int*)l, 16, 0, 0);
}

// ---------------- merged fp32 -> bf16 convert with row/col zero padding ----------
// 12 jobs in one dispatch. src: (O, Kin) fp32. dst: (Opad, Kpad) bf16, pad zeroed.
struct CvtJobs {
    const float* src[12];
    ushort_t*    dst[12];
    int O[12], Opad[12], Kin[12], Kpad[12];
    int bstart[13];
};

__global__ __launch_bounds__(256)
void cvt_all(CvtJobs jobs)
{
    int b = blockIdx.x;
    int j = 0;
    while (b >= jobs.bstart[j + 1]) ++j;
    const int t = (b - jobs.bstart[j]) * 256 + threadIdx.x;
    const int Kpad = jobs.Kpad[j];
    const int Kin  = jobs.Kin[j];
    const int cpr  = Kpad >> 3;
    if (t >= jobs.Opad[j] * cpr) return;
    const int o = t / cpr;
    const int c = t - o * cpr;
    unsigned int p0 = 0, p1 = 0, p2 = 0, p3 = 0;
    if (o < jobs.O[j] && (c * 8 + 8) <= Kin) {
        const float* s = jobs.src[j] + (size_t)o * Kin + c * 8;
        float4 f0 = reinterpret_cast<const float4*>(s)[0];
        float4 f1 = reinterpret_cast<const float4*>(s)[1];
        p0 = f2bf(f0.x) | ((unsigned int)f2bf(f0.y) << 16);
        p1 = f2bf(f0.z) | ((unsigned int)f2bf(f0.w) << 16);
        p2 = f2bf(f1.x) | ((unsigned int)f2bf(f1.y) << 16);
        p3 = f2bf(f1.z) | ((unsigned int)f2bf(f1.w) << 16);
    }
    *reinterpret_cast<uint4*>(jobs.dst[j] + (size_t)o * Kpad + c * 8) =
        make_uint4(p0, p1, p2, p3);
}

// ---------------- concat 3 biases per stream ----------------
__global__ __launch_bounds__(256)
void pack_bias(const float* __restrict__ a0, const float* __restrict__ a1,
               const float* __restrict__ a2, const float* __restrict__ b0,
               const float* __restrict__ b1, const float* __restrict__ b2,
               float* __restrict__ dv, float* __restrict__ di)
{
    int t = blockIdx.x * 256 + threadIdx.x;
    if (t >= 2064) return;
    float v, w;
    if (t < 688)       { v = a0[t];        w = b0[t]; }
    else if (t < 1376) { v = a1[t - 688];  w = b1[t - 688]; }
    else               { v = a2[t - 1376]; w = b2[t - 1376]; }
    dv[t] = v; di[t] = w;
}

// ---------------- LayerNorm (wave per row, both streams); out stride DP --------
__global__ __launch_bounds__(256)
void ln_kernel(const float* __restrict__ Xv, const float* __restrict__ Xi,
               const float* __restrict__ gv, const float* __restrict__ bv,
               const float* __restrict__ gi, const float* __restrict__ bi,
               ushort_t* __restrict__ Yv, ushort_t* __restrict__ Yi)
{
    const int lane = threadIdx.x & 63;
    const int wave = threadIdx.x >> 6;
    const long w = (long)blockIdx.x * 4 + wave;   // 0 .. 2B-1
    const float* X; const float* g; const float* b; ushort_t* Y; long r;
    if (w < B_ROWS) { X = Xv; g = gv; b = bv; Y = Yv; r = w; }
    else            { X = Xi; g = gi; b = bi; Y = Yi; r = w - B_ROWS; }

    const float4* row = reinterpret_cast<const float4*>(X + r * D_DIM);
    float4 v0 = row[lane];
    float4 v1 = row[lane + 64];
    float4 v2 = make_float4(0.f, 0.f, 0.f, 0.f);
    if (lane < 44) v2 = row[lane + 128];   // 172 float4 per row

    float s  = v0.x + v0.y + v0.z + v0.w + v1.x + v1.y + v1.z + v1.w
             + v2.x + v2.y + v2.z + v2.w;
    float s2 = v0.x*v0.x + v0.y*v0.y + v0.z*v0.z + v0.w*v0.w
             + v1.x*v1.x + v1.y*v1.y + v1.z*v1.z + v1.w*v1.w
             + v2.x*v2.x + v2.y*v2.y + v2.z*v2.z + v2.w*v2.w;
#pragma unroll
    for (int m = 32; m; m >>= 1) { s += __shfl_xor(s, m); s2 += __shfl_xor(s2, m); }

    const float mean = s * (1.f / 688.f);
    const float var  = s2 * (1.f / 688.f) - mean * mean;   // biased var
    const float rstd = rsqrtf(var + 1e-5f);

    const float4* g4 = reinterpret_cast<const float4*>(g);
    const float4* b4 = reinterpret_cast<const float4*>(b);
    ushort4* out4 = reinterpret_cast<ushort4*>(Y + r * DP);

    {
        float4 gg = g4[lane], bb = b4[lane];
        ushort4 o;
        o.x = f2bf((v0.x - mean) * rstd * gg.x + bb.x);
        o.y = f2bf((v0.y - mean) * rstd * gg.y + bb.y);
        o.z = f2bf((v0.z - mean) * rstd * gg.z + bb.z);
        o.w = f2bf((v0.w - mean) * rstd * gg.w + bb.w);
        out4[lane] = o;
    }
    {
        float4 gg = g4[lane + 64], bb = b4[lane + 64];
        ushort4 o;
        o.x = f2bf((v1.x - mean) * rstd * gg.x + bb.x);
        o.y = f2bf((v1.y - mean) * rstd * gg.y + bb.y);
        o.z = f2bf((v1.z - mean) * rstd * gg.z + bb.z);
        o.w = f2bf((v1.w - mean) * rstd * gg.w + bb.w);
        out4[lane + 64] = o;
    }
    if (lane < 44) {
        float4 gg = g4[lane + 128], bb = b4[lane + 128];
        ushort4 o;
        o.x = f2bf((v2.x - mean) * rstd * gg.x + bb.x);
        o.y = f2bf((v2.y - mean) * rstd * gg.y + bb.y);
        o.z = f2bf((v2.z - mean) * rstd * gg.z + bb.z);
        o.w = f2bf((v2.w - mean) * rstd * gg.w + bb.w);
        out4[lane + 128] = o;
    } else if (lane < 48) {
        out4[lane + 128] = make_ushort4(0, 0, 0, 0);   // zero K-pad 688..703
    }
}

// ---------------- GEMM: C(M,N) = A(M,K) @ W(N,K)^T + epilogue ----------------
// 1D grid, bijective XCD swizzle, N-fastest decode for A-strip L2 reuse.
// Guard-free staging: K%32==0; W has >= NBn*128 rows (pad rows zeroed).
// MODE 0: out bf16 = v + bias
// MODE 1: out fp32 = cA*resid + cB*(v + bias)
// MODE 2: out bf16 = gelu_exact(v + bias)
template<int MODE>
__global__ __launch_bounds__(256, 4)
void gemm2(const ushort_t* __restrict__ A0, const ushort_t* __restrict__ A1,
           const ushort_t* __restrict__ W0, const ushort_t* __restrict__ W1,
           const float* __restrict__ bias0, const float* __restrict__ bias1,
           void* __restrict__ out0, void* __restrict__ out1,
           const float* __restrict__ res0, const float* __restrict__ res1,
           const float* __restrict__ coef,
           int ca0, int cb0, int ca1, int cb1,
           int NBn, int N, int K, int lda, int ldw, int ldo)
{
    __shared__ __align__(16) ushort_t As[128 * 32];
    __shared__ __align__(16) ushort_t Bs[128 * 32];

    // XCD-aware swizzle (nwg % 8 == 0 for all our launches): XCD k gets the
    // contiguous virtual range [k*q, (k+1)*q); n varies fastest inside it.
    const int q = gridDim.x >> 3;
    const int v = (blockIdx.x & 7) * q + (blockIdx.x >> 3);
    const int nb = v % NBn;
    const int tmp = v / NBn;
    const int mb = tmp & 255;          // M/128 == 256 always here
    const int zz = tmp >> 8;

    const ushort_t* A = zz ? A1 : A0;
    const ushort_t* W = zz ? W1 : W0;
    const float* bias = zz ? bias1 : bias0;
    void* outp        = zz ? out1 : out0;
    const float* resid = zz ? res1 : res0;
    const int ca = zz ? ca1 : ca0;
    const int cb = zz ? cb1 : cb0;

    const int tid  = threadIdx.x;
    const int lane = tid & 63;
    const int wave = tid >> 6;
    const int m0 = mb * 128;
    const int n0 = nb * 128;
    const int wm = (wave >> 1) * 64;
    const int wn = (wave & 1) * 64;

    // staging: 512 x 16B segments per matrix per K-step; wave w owns segs
    // [w*128, w*128+128) via two global_load_lds issues of 64 lanes each.
    const int s0 = wave * 128 + lane;
    const int s1 = s0 + 64;
    const ushort_t* pa0 = A + (size_t)(m0 + (s0 >> 2)) * lda + (s0 & 3) * 8;
    const ushort_t* pa1 = A + (size_t)(m0 + (s1 >> 2)) * lda + (s1 & 3) * 8;
    const ushort_t* pb0 = W + (size_t)(n0 + (s0 >> 2)) * ldw + (s0 & 3) * 8;
    const ushort_t* pb1 = W + (size_t)(n0 + (s1 >> 2)) * ldw + (s1 & 3) * 8;
    ushort_t* la0 = &As[(wave * 128) * 8];        // wave-uniform LDS bases
    ushort_t* la1 = &As[(wave * 128 + 64) * 8];
    ushort_t* lb0 = &Bs[(wave * 128) * 8];
    ushort_t* lb1 = &Bs[(wave * 128 + 64) * 8];

    const f32x4 vzero = {0.f, 0.f, 0.f, 0.f};
    f32x4 acc[4][4];
#pragma unroll
    for (int i = 0; i < 4; ++i)
#pragma unroll
        for (int j = 0; j < 4; ++j)
            acc[i][j] = vzero;

    const int ko = (lane >> 4) * 8;
    const int rl = lane & 15;

    for (int kb = 0; kb < K; kb += 32) {
        gl2lds16(pa0, la0); gl2lds16(pa1, la1);
        gl2lds16(pb0, lb0); gl2lds16(pb1, lb1);
        pa0 += 32; pa1 += 32; pb0 += 32; pb1 += 32;
        __syncthreads();                 // drains vmcnt before barrier

        bf16x8 af[4], bw[4];
#pragma unroll
        for (int i = 0; i < 4; ++i) {
            af[i] = *reinterpret_cast<const bf16x8*>(&As[(wm + i * 16 + rl) * 32 + ko]);
            bw[i] = *reinterpret_cast<const bf16x8*>(&Bs[(wn + i * 16 + rl) * 32 + ko]);
        }
#pragma unroll
        for (int i = 0; i < 4; ++i)
#pragma unroll
            for (int j = 0; j < 4; ++j)
                acc[i][j] = __builtin_amdgcn_mfma_f32_16x16x32_bf16(af[i], bw[j], acc[i][j], 0, 0, 0);
        __syncthreads();
    }

    float cA = 0.f, cB = 0.f;
    if constexpr (MODE == 1) { cA = coef[ca]; cB = coef[cb]; }
    const int rb = (lane >> 4) * 4;
    const int cl = lane & 15;
#pragma unroll
    for (int j = 0; j < 4; ++j) {
        const int col = n0 + wn + j * 16 + cl;
        if (col >= N) continue;
        const float bc = bias[col];
#pragma unroll
        for (int i = 0; i < 4; ++i) {
#pragma unroll
            for (int r = 0; r < 4; ++r) {
                const int row = m0 + wm + i * 16 + rb + r;   // M%128==0: always valid
                const size_t idx = (size_t)row * ldo + col;
                float v2 = acc[i][j][r] + bc;
                if constexpr (MODE == 0) {
                    ((ushort_t*)outp)[idx] = f2bf(v2);
                } else if constexpr (MODE == 2) {
                    v2 = 0.5f * v2 * (1.0f + erff(v2 * 0.70710678118654752f));
                    ((ushort_t*)outp)[idx] = f2bf(v2);
                } else {
                    ((float*)outp)[idx] = cA * resid[idx] + cB * v2;
                }
            }
        }
    }
}

// ---------------- cross-attention over heads (wave per row) ----------------
// qkv rows stride 2064 (q|k|v of 688 each); ctx rows stride DP, K-pad zeroed.
__global__ __launch_bounds__(256)
void attn_kernel(const ushort_t* __restrict__ qkv_v, const ushort_t* __restrict__ qkv_i,
                 ushort_t* __restrict__ ctx_v, ushort_t* __restrict__ ctx_i)
{
    const int lane = threadIdx.x & 63;
    const int wave = threadIdx.x >> 6;
    const long r = (long)blockIdx.x * 4 + wave;
    const ushort_t* bv = qkv_v + r * 2064;
    const ushort_t* bi = qkv_i + r * 2064;

    float sv[4][4], si[4][4];
#pragma unroll
    for (int h = 0; h < 4; ++h)
#pragma unroll
        for (int g = 0; g < 4; ++g) { sv[h][g] = 0.f; si[h][g] = 0.f; }

    float vvr[3][4], vir[3][4];
#pragma unroll
    for (int it = 0; it < 3; ++it) {
        const int d = lane + it * 64;
        const bool ok = d < DH_DIM;
        float qv[4], kv[4], qi[4], ki[4];
#pragma unroll
        for (int h = 0; h < 4; ++h) {
            const int o = h * DH_DIM + d;
            qv[h]      = ok ? b2f(bv[o]) : 0.f;
            kv[h]      = ok ? b2f(bv[D_DIM + o]) : 0.f;
            vvr[it][h] = ok ? b2f(bv[2 * D_DIM + o]) : 0.f;
            qi[h]      = ok ? b2f(bi[o]) : 0.f;
            ki[h]      = ok ? b2f(bi[D_DIM + o]) : 0.f;
            vir[it][h] = ok ? b2f(bi[2 * D_DIM + o]) : 0.f;
        }
#pragma unroll
        for (int h = 0; h < 4; ++h)
#pragma unroll
            for (int g = 0; g < 4; ++g) {
                sv[h][g] += qi[h] * kv[g];   // att_vis scores: q_ir . k_vis
                si[h][g] += qv[h] * ki[g];   // att_ir  scores: q_vis . k_ir
            }
    }

#pragma unroll
    for (int h = 0; h < 4; ++h)
#pragma unroll
        for (int g = 0; g < 4; ++g) {
            float a = sv[h][g], b = si[h][g];
#pragma unroll
            for (int m = 32; m; m >>= 1) { a += __shfl_xor(a, m); b += __shfl_xor(b, m); }
            sv[h][g] = a; si[h][g] = b;
        }

    const float scale = 0.07624928516630235f;   // 1/sqrt(172)
    float av[4][4], ai[4][4];
#pragma unroll
    for (int h = 0; h < 4; ++h) {
        float m1 = fmaxf(fmaxf(sv[h][0], sv[h][1]), fmaxf(sv[h][2], sv[h][3])) * scale;
        float m2 = fmaxf(fmaxf(si[h][0], si[h][1]), fmaxf(si[h][2], si[h][3])) * scale;
        float d1 = 0.f, d2 = 0.f;
#pragma unroll
        for (int g = 0; g < 4; ++g) {
            av[h][g] = expf(sv[h][g] * scale - m1); d1 += av[h][g];
            ai[h][g] = expf(si[h][g] * scale - m2); d2 += ai[h][g];
        }
        const float r1 = 1.f / d1, r2 = 1.f / d2;
#pragma unroll
        for (int g = 0; g < 4; ++g) { av[h][g] *= r1; ai[h][g] *= r2; }
    }

#pragma unroll
    for (int it = 0; it < 3; ++it) {
        const int d = lane + it * 64;
        if (d < DH_DIM) {
#pragma unroll
            for (int h = 0; h < 4; ++h) {
                float cv = av[h][0] * vvr[it][0] + av[h][1] * vvr[it][1]
                         + av[h][2] * vvr[it][2] + av[h][3] * vvr[it][3];
                float ci = ai[h][0] * vir[it][0] + ai[h][1] * vir[it][1]
                         + ai[h][2] * vir[it][2] + ai[h][3] * vir[it][3];
                ctx_v[r * DP + h * DH_DIM + d] = f2bf(cv);
                ctx_i[r * DP + h * DH_DIM + d] = f2bf(ci);
            }
        }
    }
    if (lane < 16) {                       // zero K-pad 688..703
        ctx_v[r * DP + 688 + lane] = 0;
        ctx_i[r * DP + 688 + lane] = 0;
    }
}

// ---------------- host launcher ----------------
extern "C" void kernel_launch(void* const* d_in, const int* in_sizes, int n_in,
                              void* d_out, int out_size, void* d_ws, size_t ws_size,
                              hipStream_t stream)
{
    if (n_in < 35) return;
    const float* x     = (const float*)d_in[0];
    const float* x2    = (const float*)d_in[1];
    const float* Wq_v  = (const float*)d_in[2];
    const float* bq_v  = (const float*)d_in[3];
    const float* Wk_v  = (const float*)d_in[4];
    const float* bk_v  = (const float*)d_in[5];
    const float* Wv_v  = (const float*)d_in[6];
    const float* bv_v  = (const float*)d_in[7];
    const float* Wq_i  = (const float*)d_in[8];
    const float* bq_i  = (const float*)d_in[9];
    const float* Wk_i  = (const float*)d_in[10];
    const float* bk_i  = (const float*)d_in[11];
    const float* Wv_i  = (const float*)d_in[12];
    const float* bv_i  = (const float*)d_in[13];
    const float* Wo_v  = (const float*)d_in[14];
    const float* bo_v  = (const float*)d_in[15];
    const float* Wo_i  = (const float*)d_in[16];
    const float* bo_i  = (const float*)d_in[17];
    const float* ln1_g = (const float*)d_in[18];
    const float* ln1_b = (const float*)d_in[19];
    const float* ln2_g = (const float*)d_in[20];
    const float* ln2_b = (const float*)d_in[21];
    const float* ln3_g = (const float*)d_in[22];
    const float* ln3_b = (const float*)d_in[23];
    const float* ln4_g = (const float*)d_in[24];
    const float* ln4_b = (const float*)d_in[25];
    const float* m1v_W = (const float*)d_in[26];
    const float* m1v_b = (const float*)d_in[27];
    const float* m2v_W = (const float*)d_in[28];
    const float* m2v_b = (const float*)d_in[29];
    const float* m1i_W = (const float*)d_in[30];
    const float* m1i_b = (const float*)d_in[31];
    const float* m2i_W = (const float*)d_in[32];
    const float* m2i_b = (const float*)d_in[33];
    const float* coef  = (const float*)d_in[34];

    const size_t BDP = (size_t)B_ROWS * DP;
    const size_t BD  = (size_t)B_ROWS * D_DIM;

    char* ws = (char*)d_ws;
    size_t off = 0;
    auto give = [&](size_t bytes) {
        char* p = ws + off;
        off += (bytes + 255) & ~(size_t)255;
        return p;
    };
    ushort_t* Wcat_v = (ushort_t*)give(2176ull * DP * 2);
    ushort_t* Wcat_i = (ushort_t*)give(2176ull * DP * 2);
    ushort_t* Wo_vb  = (ushort_t*)give(768ull * DP * 2);
    ushort_t* Wo_ib  = (ushort_t*)give(768ull * DP * 2);
    ushort_t* m1vb   = (ushort_t*)give(128ull * DP * 2);
    ushort_t* m1ib   = (ushort_t*)give(128ull * DP * 2);
    ushort_t* m2vb   = (ushort_t*)give(768ull * 128 * 2);
    ushort_t* m2ib   = (ushort_t*)give(768ull * 128 * 2);
    float*    bcat_v = (float*)give(2064 * 4);
    float*    bcat_i = (float*)give(2064 * 4);
    // region X: xn (2*BDP bf16) -> dead after QKV gemm; reused for ctx, then h
    char* regX = give(BDP * 2 * 2);
    // region Q: qkv (2 * B * 2064 bf16)
    char* regQ = give((size_t)B_ROWS * 2064 * 2 * 2);
    // region G: mlp hidden (2 * B*128 bf16)
    char* regG = give((size_t)B_ROWS * MH_DIM * 2 * 2);
    if (ws_size < off) return;   // not enough scratch; fail loudly via validation

    ushort_t* xn_v  = (ushort_t*)regX;
    ushort_t* xn_i  = xn_v + BDP;
    ushort_t* ctx_v = xn_v;               // alias: xn dead after QKV gemm
    ushort_t* ctx_i = xn_i;
    ushort_t* h_v   = ctx_v;              // alias: ctx dead after out-proj
    ushort_t* h_i   = ctx_i;
    ushort_t* qkv_v = (ushort_t*)regQ;
    ushort_t* qkv_i = qkv_v + (size_t)B_ROWS * 2064;
    ushort_t* g_v   = (ushort_t*)regG;
    ushort_t* g_i   = g_v + (size_t)B_ROWS * MH_DIM;

    float* ov = (float*)d_out;            // out_vis fp32 lives in d_out
    float* oi = ov + BD;

    // ---- single merged weight conversion dispatch ----
    CvtJobs J;
    const float* srcs[12] = {Wq_v, Wk_v, Wv_v, Wq_i, Wk_i, Wv_i,
                             Wo_v, Wo_i, m1v_W, m1i_W, m2v_W, m2i_W};
    ushort_t* dsts[12] = {Wcat_v, Wcat_v + 688 * DP, Wcat_v + 1376 * DP,
                          Wcat_i, Wcat_i + 688 * DP, Wcat_i + 1376 * DP,
                          Wo_vb, Wo_ib, m1vb, m1ib, m2vb, m2ib};
    int Os[12]    = {688, 688, 688, 688, 688, 688, 688, 688, 128, 128, 688, 688};
    int Opads[12] = {688, 688, 800, 688, 688, 800, 768, 768, 128, 128, 768, 768};
    int Kins[12]  = {688, 688, 688, 688, 688, 688, 688, 688, 688, 688, 128, 128};
    int Kpads[12] = {DP, DP, DP, DP, DP, DP, DP, DP, DP, DP, 128, 128};
    int bs = 0;
    for (int j = 0; j < 12; ++j) {
        J.src[j] = srcs[j]; J.dst[j] = dsts[j];
        J.O[j] = Os[j]; J.Opad[j] = Opads[j]; J.Kin[j] = Kins[j]; J.Kpad[j] = Kpads[j];
        J.bstart[j] = bs;
        bs += (Opads[j] * (Kpads[j] >> 3) + 255) / 256;
    }
    J.bstart[12] = bs;
    cvt_all<<<dim3(bs), dim3(256), 0, stream>>>(J);

    pack_bias<<<dim3(9), dim3(256), 0, stream>>>(bq_v, bk_v, bv_v, bq_i, bk_i, bv_i,
                                                 bcat_v, bcat_i);

    // LN1 / LN2 -> xn (stride DP, zero pad)
    ln_kernel<<<dim3(2 * B_ROWS / 4), dim3(256), 0, stream>>>(
        x, x2, ln1_g, ln1_b, ln2_g, ln2_b, xn_v, xn_i);

    // QKV projections, both streams: (B,704) @ (2176,704)^T -> (B,2064)
    gemm2<0><<<dim3(256 * 17 * 2), dim3(256), 0, stream>>>(
        xn_v, xn_i, Wcat_v, Wcat_i, bcat_v, bcat_i, qkv_v, qkv_i,
        nullptr, nullptr, nullptr, 0, 0, 0, 0, 17, 2064, DP, DP, DP, 2064);

    // per-row 4x4 cross attention -> ctx (stride DP)
    attn_kernel<<<dim3(B_ROWS / 4), dim3(256), 0, stream>>>(qkv_v, qkv_i, ctx_v, ctx_i);

    // out projections + residual -> fp32 d_out
    gemm2<1><<<dim3(256 * 6 * 2), dim3(256), 0, stream>>>(
        ctx_v, ctx_i, Wo_vb, Wo_ib, bo_v, bo_i, ov, oi,
        x, x2, coef, 0, 1, 2, 3, 6, 688, DP, DP, DP, 688);

    // LN3 / LN4 -> h (stride DP)
    ln_kernel<<<dim3(2 * B_ROWS / 4), dim3(256), 0, stream>>>(
        ov, oi, ln3_g, ln3_b, ln4_g, ln4_b, h_v, h_i);

    // MLP fc1 + exact gelu -> g (B,128)
    gemm2<2><<<dim3(256 * 1 * 2), dim3(256), 0, stream>>>(
        h_v, h_i, m1vb, m1ib, m1v_b, m1i_b, g_v, g_i,
        nullptr, nullptr, nullptr, 0, 0, 0, 0, 1, 128, DP, DP, DP, 128);

    // MLP fc2 + final residual (in-place RMW on d_out, same-thread per element)
    gemm2<1><<<dim3(256 * 6 * 2), dim3(256), 0, stream>>>(
        g_v, g_i, m2vb, m2ib, m2v_b, m2i_b, ov, oi,
        ov, oi, coef, 4, 5, 6, 7, 6, 688, 128, 128, 128, 688);
}

// Round 4
// 690.977 us; speedup vs baseline: 2.0781x; 1.1860x over previous
//
#include <hip/hip_runtime.h>
#include <cmath>

// CrossKDDenseNet fused block for MI355X (gfx950).
// B=32768 rows, D=688 = 4 heads x 172, MLP hidden 128.
// Round 4: 2-phase double-buffered LDS staging (prefetch-before-compute),
// LDS-repacked 16B epilogue stores, bf16 out_vis intermediate.

#define B_ROWS 32768
#define D_DIM  688
#define DP     704     // padded K / activation stride
#define DH_DIM 172
#define MH_DIM 128

typedef unsigned short ushort_t;
typedef __attribute__((ext_vector_type(8))) __bf16 bf16x8;
typedef __attribute__((ext_vector_type(4))) float  f32x4;

__device__ __forceinline__ float b2f(ushort_t u) {
    return __builtin_bit_cast(float, (unsigned int)u << 16);
}
__device__ __forceinline__ ushort_t f2bf(float f) {
    unsigned int u = __builtin_bit_cast(unsigned int, f);
    u += 0x7FFFu + ((u >> 16) & 1u);   // round-to-nearest-even (finite inputs)
    return (ushort_t)(u >> 16);
}

__device__ __forceinline__ void gl2lds16(const ushort_t* g, ushort_t* l) {
    __builtin_amdgcn_global_load_lds(
        (const __attribute__((address_space(1))) unsigned int*)g,
        (__attribute__((address_space(3))) unsigned int*)l, 16, 0, 0);
}

// ---------------- merged fp32 -> bf16 convert with row/col zero padding ----------
struct CvtJobs {
    const float* src[12];
    ushort_t*    dst[12];
    int O[12], Opad[12], Kin[12], Kpad[12];
    int bstart[13];
};

__global__ __launch_bounds__(256)
void cvt_all(CvtJobs jobs)
{
    int b = blockIdx.x;
    int j = 0;
    while (b >= jobs.bstart[j + 1]) ++j;
    const int t = (b - jobs.bstart[j]) * 256 + threadIdx.x;
    const int Kpad = jobs.Kpad[j];
    const int Kin  = jobs.Kin[j];
    const int cpr  = Kpad >> 3;
    if (t >= jobs.Opad[j] * cpr) return;
    const int o = t / cpr;
    const int c = t - o * cpr;
    unsigned int p0 = 0, p1 = 0, p2 = 0, p3 = 0;
    if (o < jobs.O[j] && (c * 8 + 8) <= Kin) {
        const float* s = jobs.src[j] + (size_t)o * Kin + c * 8;
        float4 f0 = reinterpret_cast<const float4*>(s)[0];
        float4 f1 = reinterpret_cast<const float4*>(s)[1];
        p0 = f2bf(f0.x) | ((unsigned int)f2bf(f0.y) << 16);
        p1 = f2bf(f0.z) | ((unsigned int)f2bf(f0.w) << 16);
        p2 = f2bf(f1.x) | ((unsigned int)f2bf(f1.y) << 16);
        p3 = f2bf(f1.z) | ((unsigned int)f2bf(f1.w) << 16);
    }
    *reinterpret_cast<uint4*>(jobs.dst[j] + (size_t)o * Kpad + c * 8) =
        make_uint4(p0, p1, p2, p3);
}

// ---------------- concat 3 biases per stream ----------------
__global__ __launch_bounds__(256)
void pack_bias(const float* __restrict__ a0, const float* __restrict__ a1,
               const float* __restrict__ a2, const float* __restrict__ b0,
               const float* __restrict__ b1, const float* __restrict__ b2,
               float* __restrict__ dv, float* __restrict__ di)
{
    int t = blockIdx.x * 256 + threadIdx.x;
    if (t >= 2064) return;
    float v, w;
    if (t < 688)       { v = a0[t];        w = b0[t]; }
    else if (t < 1376) { v = a1[t - 688];  w = b1[t - 688]; }
    else               { v = a2[t - 1376]; w = b2[t - 1376]; }
    dv[t] = v; di[t] = w;
}

// ---------------- LayerNorm fp32-in (wave per row, both streams); out stride DP --
__global__ __launch_bounds__(256)
void ln_kernel(const float* __restrict__ Xv, const float* __restrict__ Xi,
               const float* __restrict__ gv, const float* __restrict__ bv,
               const float* __restrict__ gi, const float* __restrict__ bi,
               ushort_t* __restrict__ Yv, ushort_t* __restrict__ Yi)
{
    const int lane = threadIdx.x & 63;
    const int wave = threadIdx.x >> 6;
    const long w = (long)blockIdx.x * 4 + wave;   // 0 .. 2B-1
    const float* X; const float* g; const float* b; ushort_t* Y; long r;
    if (w < B_ROWS) { X = Xv; g = gv; b = bv; Y = Yv; r = w; }
    else            { X = Xi; g = gi; b = bi; Y = Yi; r = w - B_ROWS; }

    const float4* row = reinterpret_cast<const float4*>(X + r * D_DIM);
    float4 v0 = row[lane];
    float4 v1 = row[lane + 64];
    float4 v2 = make_float4(0.f, 0.f, 0.f, 0.f);
    if (lane < 44) v2 = row[lane + 128];   // 172 float4 per row

    float s  = v0.x + v0.y + v0.z + v0.w + v1.x + v1.y + v1.z + v1.w
             + v2.x + v2.y + v2.z + v2.w;
    float s2 = v0.x*v0.x + v0.y*v0.y + v0.z*v0.z + v0.w*v0.w
             + v1.x*v1.x + v1.y*v1.y + v1.z*v1.z + v1.w*v1.w
             + v2.x*v2.x + v2.y*v2.y + v2.z*v2.z + v2.w*v2.w;
#pragma unroll
    for (int m = 32; m; m >>= 1) { s += __shfl_xor(s, m); s2 += __shfl_xor(s2, m); }

    const float mean = s * (1.f / 688.f);
    const float var  = s2 * (1.f / 688.f) - mean * mean;   // biased var
    const float rstd = rsqrtf(var + 1e-5f);

    const float4* g4 = reinterpret_cast<const float4*>(g);
    const float4* b4 = reinterpret_cast<const float4*>(b);
    ushort4* out4 = reinterpret_cast<ushort4*>(Y + r * DP);

    {
        float4 gg = g4[lane], bb = b4[lane];
        ushort4 o;
        o.x = f2bf((v0.x - mean) * rstd * gg.x + bb.x);
        o.y = f2bf((v0.y - mean) * rstd * gg.y + bb.y);
        o.z = f2bf((v0.z - mean) * rstd * gg.z + bb.z);
        o.w = f2bf((v0.w - mean) * rstd * gg.w + bb.w);
        out4[lane] = o;
    }
    {
        float4 gg = g4[lane + 64], bb = b4[lane + 64];
        ushort4 o;
        o.x = f2bf((v1.x - mean) * rstd * gg.x + bb.x);
        o.y = f2bf((v1.y - mean) * rstd * gg.y + bb.y);
        o.z = f2bf((v1.z - mean) * rstd * gg.z + bb.z);
        o.w = f2bf((v1.w - mean) * rstd * gg.w + bb.w);
        out4[lane + 64] = o;
    }
    if (lane < 44) {
        float4 gg = g4[lane + 128], bb = b4[lane + 128];
        ushort4 o;
        o.x = f2bf((v2.x - mean) * rstd * gg.x + bb.x);
        o.y = f2bf((v2.y - mean) * rstd * gg.y + bb.y);
        o.z = f2bf((v2.z - mean) * rstd * gg.z + bb.z);
        o.w = f2bf((v2.w - mean) * rstd * gg.w + bb.w);
        out4[lane + 128] = o;
    } else if (lane < 48) {
        out4[lane + 128] = make_ushort4(0, 0, 0, 0);   // zero K-pad 688..703
    }
}

// ---------------- LayerNorm bf16-in (LN3/4); in stride 688, out stride DP -------
__global__ __launch_bounds__(256)
void ln_bf16(const ushort_t* __restrict__ Xv, const ushort_t* __restrict__ Xi,
             const float* __restrict__ gv, const float* __restrict__ bv,
             const float* __restrict__ gi, const float* __restrict__ bi,
             ushort_t* __restrict__ Yv, ushort_t* __restrict__ Yi)
{
    const int lane = threadIdx.x & 63;
    const int wave = threadIdx.x >> 6;
    const long w = (long)blockIdx.x * 4 + wave;
    const ushort_t* X; const float* g; const float* b; ushort_t* Y; long r;
    if (w < B_ROWS) { X = Xv; g = gv; b = bv; Y = Yv; r = w; }
    else            { X = Xi; g = gi; b = bi; Y = Yi; r = w - B_ROWS; }

    const ushort4* row = reinterpret_cast<const ushort4*>(X + r * D_DIM);
    ushort4 u0 = row[lane];
    ushort4 u1 = row[lane + 64];
    ushort4 u2 = make_ushort4(0, 0, 0, 0);
    if (lane < 44) u2 = row[lane + 128];

    float f0x = b2f(u0.x), f0y = b2f(u0.y), f0z = b2f(u0.z), f0w = b2f(u0.w);
    float f1x = b2f(u1.x), f1y = b2f(u1.y), f1z = b2f(u1.z), f1w = b2f(u1.w);
    float f2x = b2f(u2.x), f2y = b2f(u2.y), f2z = b2f(u2.z), f2w = b2f(u2.w);

    float s  = f0x + f0y + f0z + f0w + f1x + f1y + f1z + f1w + f2x + f2y + f2z + f2w;
    float s2 = f0x*f0x + f0y*f0y + f0z*f0z + f0w*f0w
             + f1x*f1x + f1y*f1y + f1z*f1z + f1w*f1w
             + f2x*f2x + f2y*f2y + f2z*f2z + f2w*f2w;
#pragma unroll
    for (int m = 32; m; m >>= 1) { s += __shfl_xor(s, m); s2 += __shfl_xor(s2, m); }

    const float mean = s * (1.f / 688.f);
    const float var  = s2 * (1.f / 688.f) - mean * mean;
    const float rstd = rsqrtf(var + 1e-5f);

    const float4* g4 = reinterpret_cast<const float4*>(g);
    const float4* b4 = reinterpret_cast<const float4*>(b);
    ushort4* out4 = reinterpret_cast<ushort4*>(Y + r * DP);

    {
        float4 gg = g4[lane], bb = b4[lane];
        ushort4 o;
        o.x = f2bf((f0x - mean) * rstd * gg.x + bb.x);
        o.y = f2bf((f0y - mean) * rstd * gg.y + bb.y);
        o.z = f2bf((f0z - mean) * rstd * gg.z + bb.z);
        o.w = f2bf((f0w - mean) * rstd * gg.w + bb.w);
        out4[lane] = o;
    }
    {
        float4 gg = g4[lane + 64], bb = b4[lane + 64];
        ushort4 o;
        o.x = f2bf((f1x - mean) * rstd * gg.x + bb.x);
        o.y = f2bf((f1y - mean) * rstd * gg.y + bb.y);
        o.z = f2bf((f1z - mean) * rstd * gg.z + bb.z);
        o.w = f2bf((f1w - mean) * rstd * gg.w + bb.w);
        out4[lane + 64] = o;
    }
    if (lane < 44) {
        float4 gg = g4[lane + 128], bb = b4[lane + 128];
        ushort4 o;
        o.x = f2bf((f2x - mean) * rstd * gg.x + bb.x);
        o.y = f2bf((f2y - mean) * rstd * gg.y + bb.y);
        o.z = f2bf((f2z - mean) * rstd * gg.z + bb.z);
        o.w = f2bf((f2w - mean) * rstd * gg.w + bb.w);
        out4[lane + 128] = o;
    } else if (lane < 48) {
        out4[lane + 128] = make_ushort4(0, 0, 0, 0);
    }
}

// ---------------- GEMM: C(M,N) = A(M,K) @ W(N,K)^T + epilogue ----------------
// 2-phase double-buffered global_load_lds staging; LDS-repacked 16B stores.
// MODE 0: out bf16 = v + bias                         (QKV)
// MODE 1: out bf16 = cA*resid_f32 + cB*(v + bias)     (out-proj)
// MODE 2: out bf16 = gelu_exact(v + bias)             (MLP1)
// MODE 3: out f32  = cA*resid_bf16 + cB*(v + bias)    (MLP2 final)
template<int MODE>
__global__ __launch_bounds__(256, 4)
void gemm2(const ushort_t* __restrict__ A0, const ushort_t* __restrict__ A1,
           const ushort_t* __restrict__ W0, const ushort_t* __restrict__ W1,
           const float* __restrict__ bias0, const float* __restrict__ bias1,
           void* __restrict__ out0, void* __restrict__ out1,
           const void* __restrict__ res0, const void* __restrict__ res1,
           const float* __restrict__ coef,
           int ca0, int cb0, int ca1, int cb1,
           int NBn, int N, int K, int lda, int ldw, int ldo)
{
    __shared__ __align__(16) ushort_t smem[16384];   // 32 KB: As[2][4096] | Bs[2][4096]
    ushort_t* As = smem;
    ushort_t* Bs = smem + 8192;

    // bijective XCD swizzle (grid % 8 == 0), n fastest for A-strip L2 reuse
    const int q  = gridDim.x >> 3;
    const int vb = (blockIdx.x & 7) * q + (blockIdx.x >> 3);
    const int nb = vb % NBn;
    const int tmp = vb / NBn;
    const int mb = tmp & 255;          // M/128 == 256 always here
    const int zz = tmp >> 8;

    const ushort_t* A = zz ? A1 : A0;
    const ushort_t* W = zz ? W1 : W0;
    const float* bias = zz ? bias1 : bias0;
    void* outp        = zz ? out1 : out0;
    const void* resid = zz ? res1 : res0;
    const int ca = zz ? ca1 : ca0;
    const int cb = zz ? cb1 : cb0;

    const int tid  = threadIdx.x;
    const int lane = tid & 63;
    const int wave = tid >> 6;
    const int m0 = mb * 128;
    const int n0 = nb * 128;
    const int wm = (wave >> 1) * 64;
    const int wn = (wave & 1) * 64;

    // staging: 512 x 16B segments per matrix per K-step; wave w owns segments
    // [w*128, w*128+128) via two global_load_lds issues of 64 lanes each.
    const int s0 = wave * 128 + lane;
    const int s1 = s0 + 64;
    const ushort_t* pa0 = A + (size_t)(m0 + (s0 >> 2)) * lda + (s0 & 3) * 8;
    const ushort_t* pa1 = A + (size_t)(m0 + (s1 >> 2)) * lda + (s1 & 3) * 8;
    const ushort_t* pb0 = W + (size_t)(n0 + (s0 >> 2)) * ldw + (s0 & 3) * 8;
    const ushort_t* pb1 = W + (size_t)(n0 + (s1 >> 2)) * ldw + (s1 & 3) * 8;

    const f32x4 vzero = {0.f, 0.f, 0.f, 0.f};
    f32x4 acc[4][4];
#pragma unroll
    for (int i = 0; i < 4; ++i)
#pragma unroll
        for (int j = 0; j < 4; ++j)
            acc[i][j] = vzero;

    const int ko = (lane >> 4) * 8;
    const int rl = lane & 15;
    const int nkt = K / 32;

    auto stage = [&](int buf, int kt) {
        const int kof = kt * 32;
        ushort_t* ad = As + buf * 4096 + wave * 1024;   // wave-uniform LDS bases
        ushort_t* bd = Bs + buf * 4096 + wave * 1024;
        gl2lds16(pa0 + kof, ad);
        gl2lds16(pa1 + kof, ad + 512);
        gl2lds16(pb0 + kof, bd);
        gl2lds16(pb1 + kof, bd + 512);
    };

    stage(0, 0);
    __syncthreads();                     // drain prologue loads

    for (int kt = 0; kt < nkt; ++kt) {
        const int cur = kt & 1;
        if (kt + 1 < nkt) stage(cur ^ 1, kt + 1);   // prefetch next tile (issue only)

        const ushort_t* Ab = As + cur * 4096;
        const ushort_t* Bb = Bs + cur * 4096;
        bf16x8 af[4], bw[4];
#pragma unroll
        for (int i = 0; i < 4; ++i) {
            af[i] = *reinterpret_cast<const bf16x8*>(&Ab[(wm + i * 16 + rl) * 32 + ko]);
            bw[i] = *reinterpret_cast<const bf16x8*>(&Bb[(wn + i * 16 + rl) * 32 + ko]);
        }
#pragma unroll
        for (int i = 0; i < 4; ++i)
#pragma unroll
            for (int j = 0; j < 4; ++j)
                acc[i][j] = __builtin_amdgcn_mfma_f32_16x16x32_bf16(af[i], bw[j], acc[i][j], 0, 0, 0);
        __syncthreads();                 // drains vmcnt(0): next buf ready; cur reusable
    }

    // ---- epilogue: repack C through LDS, then 16B stores ----
    float cA = 0.f, cB = 1.f;
    if constexpr (MODE == 1 || MODE == 3) { cA = coef[ca]; cB = coef[cb]; }
    const int rb = (lane >> 4) * 4;
    const int cl = lane & 15;
    ushort_t* C = smem;                  // 128 x 128 bf16 = 32 KB (overlays As/Bs)
#pragma unroll
    for (int j = 0; j < 4; ++j) {
        const int lcol = wn + j * 16 + cl;
        const int col = n0 + lcol;
        const float bc = (col < N) ? bias[col] : 0.f;
#pragma unroll
        for (int i = 0; i < 4; ++i) {
            const int lrow = wm + i * 16 + rb;
#pragma unroll
            for (int r = 0; r < 4; ++r) {
                float val = acc[i][j][r] + bc;
                if constexpr (MODE == 2)
                    val = 0.5f * val * (1.0f + erff(val * 0.70710678118654752f));
                C[(lrow + r) * 128 + lcol] = f2bf(val);
            }
        }
    }
    __syncthreads();

#pragma unroll
    for (int p = 0; p < 8; ++p) {
        const int c = tid + p * 256;     // 2048 chunks of 8 elems
        const int lrow = c >> 4;
        const int lcl = (c & 15) * 8;
        const int gcol = n0 + lcl;
        if (gcol >= N) continue;         // N % 8 == 0 in all uses
        const size_t idx = (size_t)(m0 + lrow) * ldo + gcol;
        uint4 pv = *reinterpret_cast<const uint4*>(&C[lrow * 128 + lcl]);
        if constexpr (MODE == 0 || MODE == 2) {
            *reinterpret_cast<uint4*>((ushort_t*)outp + idx) = pv;
        } else if constexpr (MODE == 1) {
            const float* rp = (const float*)resid + idx;
            float4 r0 = reinterpret_cast<const float4*>(rp)[0];
            float4 r1 = reinterpret_cast<const float4*>(rp)[1];
            float rr[8] = {r0.x, r0.y, r0.z, r0.w, r1.x, r1.y, r1.z, r1.w};
            const ushort_t* pu = (const ushort_t*)&pv;
            ushort_t o[8];
#pragma unroll
            for (int k = 0; k < 8; ++k)
                o[k] = f2bf(cA * rr[k] + cB * b2f(pu[k]));
            *reinterpret_cast<uint4*>((ushort_t*)outp + idx) = *reinterpret_cast<uint4*>(o);
        } else {                         // MODE 3: fp32 out, bf16 resid
            uint4 rv = *reinterpret_cast<const uint4*>((const ushort_t*)resid + idx);
            const ushort_t* pu = (const ushort_t*)&pv;
            const ushort_t* ru = (const ushort_t*)&rv;
            float o[8];
#pragma unroll
            for (int k = 0; k < 8; ++k)
                o[k] = cA * b2f(ru[k]) + cB * b2f(pu[k]);
            float4* op = reinterpret_cast<float4*>((float*)outp + idx);
            op[0] = make_float4(o[0], o[1], o[2], o[3]);
            op[1] = make_float4(o[4], o[5], o[6], o[7]);
        }
    }
}

// ---------------- cross-attention over heads (wave per row) ----------------
__global__ __launch_bounds__(256)
void attn_kernel(const ushort_t* __restrict__ qkv_v, const ushort_t* __restrict__ qkv_i,
                 ushort_t* __restrict__ ctx_v, ushort_t* __restrict__ ctx_i)
{
    const int lane = threadIdx.x & 63;
    const int wave = threadIdx.x >> 6;
    const long r = (long)blockIdx.x * 4 + wave;
    const ushort_t* bv = qkv_v + r * 2064;
    const ushort_t* bi = qkv_i + r * 2064;

    float sv[4][4], si[4][4];
#pragma unroll
    for (int h = 0; h < 4; ++h)
#pragma unroll
        for (int g = 0; g < 4; ++g) { sv[h][g] = 0.f; si[h][g] = 0.f; }

    float vvr[3][4], vir[3][4];
#pragma unroll
    for (int it = 0; it < 3; ++it) {
        const int d = lane + it * 64;
        const bool ok = d < DH_DIM;
        float qv[4], kv[4], qi[4], ki[4];
#pragma unroll
        for (int h = 0; h < 4; ++h) {
            const int o = h * DH_DIM + d;
            qv[h]      = ok ? b2f(bv[o]) : 0.f;
            kv[h]      = ok ? b2f(bv[D_DIM + o]) : 0.f;
            vvr[it][h] = ok ? b2f(bv[2 * D_DIM + o]) : 0.f;
            qi[h]      = ok ? b2f(bi[o]) : 0.f;
            ki[h]      = ok ? b2f(bi[D_DIM + o]) : 0.f;
            vir[it][h] = ok ? b2f(bi[2 * D_DIM + o]) : 0.f;
        }
#pragma unroll
        for (int h = 0; h < 4; ++h)
#pragma unroll
            for (int g = 0; g < 4; ++g) {
                sv[h][g] += qi[h] * kv[g];   // att_vis scores: q_ir . k_vis
                si[h][g] += qv[h] * ki[g];   // att_ir  scores: q_vis . k_ir
            }
    }

#pragma unroll
    for (int h = 0; h < 4; ++h)
#pragma unroll
        for (int g = 0; g < 4; ++g) {
            float a = sv[h][g], b = si[h][g];
#pragma unroll
            for (int m = 32; m; m >>= 1) { a += __shfl_xor(a, m); b += __shfl_xor(b, m); }
            sv[h][g] = a; si[h][g] = b;
        }

    const float scale = 0.07624928516630235f;   // 1/sqrt(172)
    float av[4][4], ai[4][4];
#pragma unroll
    for (int h = 0; h < 4; ++h) {
        float m1 = fmaxf(fmaxf(sv[h][0], sv[h][1]), fmaxf(sv[h][2], sv[h][3])) * scale;
        float m2 = fmaxf(fmaxf(si[h][0], si[h][1]), fmaxf(si[h][2], si[h][3])) * scale;
        float d1 = 0.f, d2 = 0.f;
#pragma unroll
        for (int g = 0; g < 4; ++g) {
            av[h][g] = expf(sv[h][g] * scale - m1); d1 += av[h][g];
            ai[h][g] = expf(si[h][g] * scale - m2); d2 += ai[h][g];
        }
        const float r1 = 1.f / d1, r2 = 1.f / d2;
#pragma unroll
        for (int g = 0; g < 4; ++g) { av[h][g] *= r1; ai[h][g] *= r2; }
    }

#pragma unroll
    for (int it = 0; it < 3; ++it) {
        const int d = lane + it * 64;
        if (d < DH_DIM) {
#pragma unroll
            for (int h = 0; h < 4; ++h) {
                float cv = av[h][0] * vvr[it][0] + av[h][1] * vvr[it][1]
                         + av[h][2] * vvr[it][2] + av[h][3] * vvr[it][3];
                float ci = ai[h][0] * vir[it][0] + ai[h][1] * vir[it][1]
                         + ai[h][2] * vir[it][2] + ai[h][3] * vir[it][3];
                ctx_v[r * DP + h * DH_DIM + d] = f2bf(cv);
                ctx_i[r * DP + h * DH_DIM + d] = f2bf(ci);
            }
        }
    }
    if (lane < 16) {                       // zero K-pad 688..703
        ctx_v[r * DP + 688 + lane] = 0;
        ctx_i[r * DP + 688 + lane] = 0;
    }
}

// ---------------- host launcher ----------------
extern "C" void kernel_launch(void* const* d_in, const int* in_sizes, int n_in,
                              void* d_out, int out_size, void* d_ws, size_t ws_size,
                              hipStream_t stream)
{
    if (n_in < 35) return;
    const float* x     = (const float*)d_in[0];
    const float* x2    = (const float*)d_in[1];
    const float* Wq_v  = (const float*)d_in[2];
    const float* bq_v  = (const float*)d_in[3];
    const float* Wk_v  = (const float*)d_in[4];
    const float* bk_v  = (const float*)d_in[5];
    const float* Wv_v  = (const float*)d_in[6];
    const float* bv_v  = (const float*)d_in[7];
    const float* Wq_i  = (const float*)d_in[8];
    const float* bq_i  = (const float*)d_in[9];
    const float* Wk_i  = (const float*)d_in[10];
    const float* bk_i  = (const float*)d_in[11];
    const float* Wv_i  = (const float*)d_in[12];
    const float* bv_i  = (const float*)d_in[13];
    const float* Wo_v  = (const float*)d_in[14];
    const float* bo_v  = (const float*)d_in[15];
    const float* Wo_i  = (const float*)d_in[16];
    const float* bo_i  = (const float*)d_in[17];
    const float* ln1_g = (const float*)d_in[18];
    const float* ln1_b = (const float*)d_in[19];
    const float* ln2_g = (const float*)d_in[20];
    const float* ln2_b = (const float*)d_in[21];
    const float* ln3_g = (const float*)d_in[22];
    const float* ln3_b = (const float*)d_in[23];
    const float* ln4_g = (const float*)d_in[24];
    const float* ln4_b = (const float*)d_in[25];
    const float* m1v_W = (const float*)d_in[26];
    const float* m1v_b = (const float*)d_in[27];
    const float* m2v_W = (const float*)d_in[28];
    const float* m2v_b = (const float*)d_in[29];
    const float* m1i_W = (const float*)d_in[30];
    const float* m1i_b = (const float*)d_in[31];
    const float* m2i_W = (const float*)d_in[32];
    const float* m2i_b = (const float*)d_in[33];
    const float* coef  = (const float*)d_in[34];

    const size_t BDP = (size_t)B_ROWS * DP;
    const size_t BD  = (size_t)B_ROWS * D_DIM;

    char* ws = (char*)d_ws;
    size_t off = 0;
    auto give = [&](size_t bytes) {
        char* p = ws + off;
        off += (bytes + 255) & ~(size_t)255;
        return p;
    };
    ushort_t* Wcat_v = (ushort_t*)give(2176ull * DP * 2);
    ushort_t* Wcat_i = (ushort_t*)give(2176ull * DP * 2);
    ushort_t* Wo_vb  = (ushort_t*)give(768ull * DP * 2);
    ushort_t* Wo_ib  = (ushort_t*)give(768ull * DP * 2);
    ushort_t* m1vb   = (ushort_t*)give(128ull * DP * 2);
    ushort_t* m1ib   = (ushort_t*)give(128ull * DP * 2);
    ushort_t* m2vb   = (ushort_t*)give(768ull * 128 * 2);
    ushort_t* m2ib   = (ushort_t*)give(768ull * 128 * 2);
    float*    bcat_v = (float*)give(2064 * 4);
    float*    bcat_i = (float*)give(2064 * 4);
    // region X: xn (2*BDP bf16) -> dead after QKV gemm; reused for ctx, then h
    char* regX = give(BDP * 2 * 2);
    // region Q: qkv (2 * B * 2064 bf16) -> dead after attn; reused for bf16 out_vis/ir
    char* regQ = give((size_t)B_ROWS * 2064 * 2 * 2);
    // region G: mlp hidden (2 * B*128 bf16)
    char* regG = give((size_t)B_ROWS * MH_DIM * 2 * 2);
    if (ws_size < off) return;   // not enough scratch; fail loudly via validation

    ushort_t* xn_v  = (ushort_t*)regX;
    ushort_t* xn_i  = xn_v + BDP;
    ushort_t* ctx_v = xn_v;               // alias: xn dead after QKV gemm
    ushort_t* ctx_i = xn_i;
    ushort_t* h_v   = ctx_v;              // alias: ctx dead after out-proj
    ushort_t* h_i   = ctx_i;
    ushort_t* qkv_v = (ushort_t*)regQ;
    ushort_t* qkv_i = qkv_v + (size_t)B_ROWS * 2064;
    ushort_t* ovb   = (ushort_t*)regQ;    // alias: qkv dead after attn; bf16 out_vis
    ushort_t* oib   = ovb + BD;           // bf16 out_ir, stride 688
    ushort_t* g_v   = (ushort_t*)regG;
    ushort_t* g_i   = g_v + (size_t)B_ROWS * MH_DIM;

    float* ov = (float*)d_out;            // final fp32 outputs
    float* oi = ov + BD;

    // ---- single merged weight conversion dispatch ----
    CvtJobs J;
    const float* srcs[12] = {Wq_v, Wk_v, Wv_v, Wq_i, Wk_i, Wv_i,
                             Wo_v, Wo_i, m1v_W, m1i_W, m2v_W, m2i_W};
    ushort_t* dsts[12] = {Wcat_v, Wcat_v + 688 * DP, Wcat_v + 1376 * DP,
                          Wcat_i, Wcat_i + 688 * DP, Wcat_i + 1376 * DP,
                          Wo_vb, Wo_ib, m1vb, m1ib, m2vb, m2ib};
    int Os[12]    = {688, 688, 688, 688, 688, 688, 688, 688, 128, 128, 688, 688};
    int Opads[12] = {688, 688, 800, 688, 688, 800, 768, 768, 128, 128, 768, 768};
    int Kins[12]  = {688, 688, 688, 688, 688, 688, 688, 688, 688, 688, 128, 128};
    int Kpads[12] = {DP, DP, DP, DP, DP, DP, DP, DP, DP, DP, 128, 128};
    int bs = 0;
    for (int j = 0; j < 12; ++j) {
        J.src[j] = srcs[j]; J.dst[j] = dsts[j];
        J.O[j] = Os[j]; J.Opad[j] = Opads[j]; J.Kin[j] = Kins[j]; J.Kpad[j] = Kpads[j];
        J.bstart[j] = bs;
        bs += (Opads[j] * (Kpads[j] >> 3) + 255) / 256;
    }
    J.bstart[12] = bs;
    cvt_all<<<dim3(bs), dim3(256), 0, stream>>>(J);

    pack_bias<<<dim3(9), dim3(256), 0, stream>>>(bq_v, bk_v, bv_v, bq_i, bk_i, bv_i,
                                                 bcat_v, bcat_i);

    // LN1 / LN2 -> xn (stride DP, zero pad)
    ln_kernel<<<dim3(2 * B_ROWS / 4), dim3(256), 0, stream>>>(
        x, x2, ln1_g, ln1_b, ln2_g, ln2_b, xn_v, xn_i);

    // QKV projections, both streams: (B,704) @ (2176,704)^T -> (B,2064) bf16
    gemm2<0><<<dim3(256 * 17 * 2), dim3(256), 0, stream>>>(
        xn_v, xn_i, Wcat_v, Wcat_i, bcat_v, bcat_i, qkv_v, qkv_i,
        nullptr, nullptr, nullptr, 0, 0, 0, 0, 17, 2064, DP, DP, DP, 2064);

    // per-row 4x4 cross attention -> ctx (stride DP)
    attn_kernel<<<dim3(B_ROWS / 4), dim3(256), 0, stream>>>(qkv_v, qkv_i, ctx_v, ctx_i);

    // out projections + residual -> bf16 out_vis/ir (stride 688, aliases dead qkv)
    gemm2<1><<<dim3(256 * 6 * 2), dim3(256), 0, stream>>>(
        ctx_v, ctx_i, Wo_vb, Wo_ib, bo_v, bo_i, ovb, oib,
        x, x2, coef, 0, 1, 2, 3, 6, 688, DP, DP, DP, 688);

    // LN3 / LN4 (bf16 in) -> h (stride DP)
    ln_bf16<<<dim3(2 * B_ROWS / 4), dim3(256), 0, stream>>>(
        ovb, oib, ln3_g, ln3_b, ln4_g, ln4_b, h_v, h_i);

    // MLP fc1 + exact gelu -> g (B,128) bf16
    gemm2<2><<<dim3(256 * 1 * 2), dim3(256), 0, stream>>>(
        h_v, h_i, m1vb, m1ib, m1v_b, m1i_b, g_v, g_i,
        nullptr, nullptr, nullptr, 0, 0, 0, 0, 1, 128, DP, DP, DP, 128);

    // MLP fc2 + final residual -> fp32 d_out (reads bf16 resid, writes fp32)
    gemm2<3><<<dim3(256 * 6 * 2), dim3(256), 0, stream>>>(
        g_v, g_i, m2vb, m2ib, m2v_b, m2i_b, ov, oi,
        ovb, oib, coef, 4, 5, 6, 7, 6, 688, 128, 128, 128, 688);
}